// Round 2
// baseline (1474.892 us; speedup 1.0000x reference)
//
#include <hip/hip_runtime.h>
#include <math.h>

// Causal attention, fp32, B=2 H=16 L=2048 D=64, scale = 1 (TEMPERATURE).
// Baseline: 1 thread = 1 query row, flash-style online softmax.
// Block = 128 threads, processes chunk c and its causal mirror chunk
// Lq-(c+1)*128 in two sequential phases -> every block does exactly 34
// key-tiles (perfect causal load balance).
// R1 fix: 8 chunk-pairs per head (not 16): c = blk & 7, bh = blk >> 3.

constexpr int Lq = 2048;
constexpr int Dd = 64;
constexpr int KT = 64;        // keys per LDS tile
constexpr int THREADS = 128;  // rows per phase
constexpr int PAIRS = Lq / (2 * THREADS);  // 8 mirror chunk-pairs per head

__global__ __launch_bounds__(THREADS)
void causal_attn_kernel(const float* __restrict__ Q, const float* __restrict__ K,
                        const float* __restrict__ V, float* __restrict__ O) {
  __shared__ float ks[KT][Dd];
  __shared__ float vs[KT][Dd];
  const int tid = threadIdx.x;
  const int blk = blockIdx.x;
  const int c  = blk & (PAIRS - 1);  // 0..7
  const int bh = blk / PAIRS;        // 0..31
  const size_t base = (size_t)bh * Lq * Dd;
  const float* Kb = K + base;
  const float* Vb = V + base;
  const float* Qb = Q + base;
  float*       Ob = O + base;

  #pragma unroll 1
  for (int phase = 0; phase < 2; ++phase) {
    const int row0 = (phase == 0) ? (c * THREADS) : (Lq - (c + 1) * THREADS);
    const int row  = row0 + tid;

    // q row -> registers
    float qr[Dd];
    #pragma unroll
    for (int i = 0; i < Dd / 4; ++i) {
      const float4 t4 = *reinterpret_cast<const float4*>(Qb + (size_t)row * Dd + i * 4);
      qr[i * 4 + 0] = t4.x; qr[i * 4 + 1] = t4.y;
      qr[i * 4 + 2] = t4.z; qr[i * 4 + 3] = t4.w;
    }

    float m = -INFINITY;
    float l = 0.f;
    float acc[Dd];
    #pragma unroll
    for (int i = 0; i < Dd; ++i) acc[i] = 0.f;

    const int kend = row0 + THREADS;  // uniform across block
    #pragma unroll 1
    for (int t = 0; t < kend; t += KT) {
      __syncthreads();  // all readers of previous tile done
      // stage K/V tile: 64 keys x 64 dims, 8 float4 each per thread, coalesced
      #pragma unroll
      for (int i = 0; i < (KT * Dd / 4) / THREADS; ++i) {
        const int idx = tid + i * THREADS;
        reinterpret_cast<float4*>(&ks[0][0])[idx] =
            reinterpret_cast<const float4*>(Kb + (size_t)t * Dd)[idx];
        reinterpret_cast<float4*>(&vs[0][0])[idx] =
            reinterpret_cast<const float4*>(Vb + (size_t)t * Dd)[idx];
      }
      __syncthreads();

      const int jmax = min(KT, row - t + 1);  // causal bound (may be <=0)
      for (int j = 0; j < jmax; ++j) {
        // s = dot(q, k_j): 4 independent FMA chains; uniform-address LDS
        // reads across the wave -> broadcast, no bank conflicts.
        const float4* kj = reinterpret_cast<const float4*>(&ks[j][0]);
        float sacc[4] = {0.f, 0.f, 0.f, 0.f};
        #pragma unroll
        for (int i = 0; i < 16; ++i) {
          const float4 a = kj[i];
          sacc[i & 3] += qr[i * 4 + 0] * a.x + qr[i * 4 + 1] * a.y +
                         qr[i * 4 + 2] * a.z + qr[i * 4 + 3] * a.w;
        }
        const float s = (sacc[0] + sacc[1]) + (sacc[2] + sacc[3]);

        const float4* vj = reinterpret_cast<const float4*>(&vs[j][0]);
        if (s <= m) {
          // common path: running max unchanged
          const float p = __expf(s - m);
          l += p;
          #pragma unroll
          for (int i = 0; i < 16; ++i) {
            const float4 a = vj[i];
            acc[i * 4 + 0] += p * a.x;
            acc[i * 4 + 1] += p * a.y;
            acc[i * 4 + 2] += p * a.z;
            acc[i * 4 + 3] += p * a.w;
          }
        } else {
          // new max: rescale. First key: m=-inf -> corr=exp(-inf)=0.
          const float corr = __expf(m - s);
          m = s;
          l = l * corr + 1.f;  // p(new max) = 1
          #pragma unroll
          for (int i = 0; i < 16; ++i) {
            const float4 a = vj[i];
            acc[i * 4 + 0] = acc[i * 4 + 0] * corr + a.x;
            acc[i * 4 + 1] = acc[i * 4 + 1] * corr + a.y;
            acc[i * 4 + 2] = acc[i * 4 + 2] * corr + a.z;
            acc[i * 4 + 3] = acc[i * 4 + 3] * corr + a.w;
          }
        }
      }
    }

    const float inv = 1.f / l;  // l >= 1 always (every row sees its own key)
    #pragma unroll
    for (int i = 0; i < Dd / 4; ++i) {
      float4 t4;
      t4.x = acc[i * 4 + 0] * inv;
      t4.y = acc[i * 4 + 1] * inv;
      t4.z = acc[i * 4 + 2] * inv;
      t4.w = acc[i * 4 + 3] * inv;
      *reinterpret_cast<float4*>(Ob + (size_t)row * Dd + i * 4) = t4;
    }
  }
}

extern "C" void kernel_launch(void* const* d_in, const int* in_sizes, int n_in,
                              void* d_out, int out_size, void* d_ws, size_t ws_size,
                              hipStream_t stream) {
  const float* q = (const float*)d_in[0];
  const float* k = (const float*)d_in[1];
  const float* v = (const float*)d_in[2];
  float* o = (float*)d_out;
  const int bh_count = in_sizes[0] / (Lq * Dd);  // B*H = 32
  const int grid = bh_count * PAIRS;             // 32 * 8 = 256 blocks
  causal_attn_kernel<<<dim3((unsigned)grid), dim3(THREADS), 0, stream>>>(q, k, v, o);
  (void)d_ws; (void)ws_size; (void)n_in; (void)out_size;
}

// Round 4
// 141.424 us; speedup vs baseline: 10.4289x; 10.4289x over previous
//
#include <hip/hip_runtime.h>
#include <math.h>

// Causal attention, B=2 H=16 L=2048 D=64, fp32 in/out, scale=1.
// MFMA flash attention: 4-wave blocks, 16 q-rows/wave, KVBLK=64.
// mfma_f32_16x16x32_bf16; C/D layout col=lane&15, row=4*(lane>>4)+reg.
// LDS XOR-swizzle (row&7)<<4 on all 128B-row tiles (G4).
// Mirror-paired chunks: block does chunks c and 31-c -> 33 tiles each.
// R4: split-bf16 QK^T (S = Qh*Kh + Ql*Kh + Qh*Kl) for fp32-accurate scores;
//     PV stays single bf16 (error ~0.004).

typedef __attribute__((ext_vector_type(8))) short bf16x8;
typedef __attribute__((ext_vector_type(4))) float f32x4;
typedef __attribute__((ext_vector_type(4))) short short4v;

constexpr int Lq = 2048;
constexpr int Dd = 64;
constexpr int KT = 64;              // keys per LDS tile
constexpr int THREADS = 256;        // 4 waves
constexpr int CHUNK = 64;           // q rows per block chunk
constexpr int NCHUNK = Lq / CHUNK;  // 32
constexpr int PAIRS = NCHUNK / 2;   // 16

static __device__ __forceinline__ unsigned short f2bf(float f) {
  unsigned u = __builtin_bit_cast(unsigned, f);
  u = u + 0x7fffu + ((u >> 16) & 1u);  // RNE
  return (unsigned short)(u >> 16);
}
static __device__ __forceinline__ float bf2f(unsigned short h) {
  return __builtin_bit_cast(float, ((unsigned)h) << 16);
}

// swizzled byte offset inside a [row][128B] LDS tile
#define SWZB(row, bcol) ((((row) * 128) + (bcol)) ^ (((row) & 7) << 4))

__global__ __launch_bounds__(THREADS)
void causal_attn_mfma(const float* __restrict__ Q, const float* __restrict__ K,
                      const float* __restrict__ V, float* __restrict__ O) {
  __shared__ char ksh[KT * 128];      // K tile hi [key][d] bf16, swizzled
  __shared__ char ksl[KT * 128];      // K tile lo
  __shared__ char vt[Dd * 128];       // V tile transposed [d][key] bf16, swizzled
  __shared__ char pl[4][16 * 128];    // per-wave P [q][key] bf16, swizzled

  const int tid  = threadIdx.x;
  const int lane = tid & 63;
  const int wv   = tid >> 6;
  const int l15  = lane & 15;
  const int g    = lane >> 4;

  const int bh = blockIdx.x / PAIRS;
  const int pr = blockIdx.x % PAIRS;
  const size_t base = (size_t)bh * Lq * Dd;
  const float* Qb = Q + base;
  const float* Kb = K + base;
  const float* Vb = V + base;
  float*       Ob = O + base;
  char* pw = pl[wv];

  #pragma unroll 1
  for (int phase = 0; phase < 2; ++phase) {
    const int chunk = (phase == 0) ? pr : (NCHUNK - 1 - pr);
    const int row0  = chunk * CHUNK;
    const int T     = chunk + 1;          // key tiles for this chunk
    const int qrow  = row0 + wv * 16;     // wave's first q row

    // ---- Q fragments (A-operand), split hi/lo:
    // lane holds Q[qrow+l15][kk*32+g*8 .. +7]
    bf16x8 qh[2], ql[2];
    #pragma unroll
    for (int kk = 0; kk < 2; ++kk) {
      const float* qp = Qb + (size_t)(qrow + l15) * Dd + kk * 32 + g * 8;
      const float4 a = *reinterpret_cast<const float4*>(qp);
      const float4 b = *reinterpret_cast<const float4*>(qp + 4);
      float e[8] = {a.x, a.y, a.z, a.w, b.x, b.y, b.z, b.w};
      bf16x8 h8, l8;
      #pragma unroll
      for (int i = 0; i < 8; ++i) {
        const unsigned short h = f2bf(e[i]);
        h8[i] = (short)h;
        l8[i] = (short)f2bf(e[i] - bf2f(h));
      }
      qh[kk] = h8;
      ql[kk] = l8;
    }

    float m[4], lsum[4];
    f32x4 o[4];
    #pragma unroll
    for (int r = 0; r < 4; ++r) { m[r] = -INFINITY; lsum[r] = 0.f; }
    #pragma unroll
    for (int nd = 0; nd < 4; ++nd) o[nd] = f32x4{0.f, 0.f, 0.f, 0.f};

    #pragma unroll 1
    for (int t = 0; t < T; ++t) {
      __syncthreads();  // previous tile fully consumed
      // ---- stage K tile (hi+lo): 1024 float4s; thread gets 4
      #pragma unroll
      for (int i = 0; i < 4; ++i) {
        const int c   = tid + i * 256;   // float4 index in 64x64 tile
        const int row = c >> 4;
        const int ch  = c & 15;
        const float4 f = *reinterpret_cast<const float4*>(
            Kb + (size_t)(t * KT + row) * Dd + ch * 4);
        float e[4] = {f.x, f.y, f.z, f.w};
        short4v sh, sl;
        #pragma unroll
        for (int j = 0; j < 4; ++j) {
          const unsigned short h = f2bf(e[j]);
          sh[j] = (short)h;
          sl[j] = (short)f2bf(e[j] - bf2f(h));
        }
        *reinterpret_cast<short4v*>(ksh + SWZB(row, ch * 8)) = sh;
        *reinterpret_cast<short4v*>(ksl + SWZB(row, ch * 8)) = sl;
      }
      // ---- stage V transposed: thread owns key=tid&63, d-quarter tid>>6
      {
        const int key = tid & 63;
        const int q4  = tid >> 6;
        #pragma unroll
        for (int i = 0; i < 4; ++i) {
          const int d0 = q4 * 16 + i * 4;
          const float4 f = *reinterpret_cast<const float4*>(
              Vb + (size_t)(t * KT + key) * Dd + d0);
          *reinterpret_cast<unsigned short*>(vt + SWZB(d0 + 0, key * 2)) = f2bf(f.x);
          *reinterpret_cast<unsigned short*>(vt + SWZB(d0 + 1, key * 2)) = f2bf(f.y);
          *reinterpret_cast<unsigned short*>(vt + SWZB(d0 + 2, key * 2)) = f2bf(f.z);
          *reinterpret_cast<unsigned short*>(vt + SWZB(d0 + 3, key * 2)) = f2bf(f.w);
        }
      }
      __syncthreads();

      // ---- S = Q K^T (split-bf16, 3 passes): 4 key-subtiles x 2 k-chunks
      f32x4 s[4];
      #pragma unroll
      for (int n = 0; n < 4; ++n) s[n] = f32x4{0.f, 0.f, 0.f, 0.f};
      #pragma unroll
      for (int kk = 0; kk < 2; ++kk) {
        #pragma unroll
        for (int n = 0; n < 4; ++n) {
          const bf16x8 kfh = *reinterpret_cast<const bf16x8*>(
              ksh + SWZB(n * 16 + l15, kk * 64 + g * 16));
          const bf16x8 kfl = *reinterpret_cast<const bf16x8*>(
              ksl + SWZB(n * 16 + l15, kk * 64 + g * 16));
          s[n] = __builtin_amdgcn_mfma_f32_16x16x32_bf16(qh[kk], kfh, s[n], 0, 0, 0);
          s[n] = __builtin_amdgcn_mfma_f32_16x16x32_bf16(ql[kk], kfh, s[n], 0, 0, 0);
          s[n] = __builtin_amdgcn_mfma_f32_16x16x32_bf16(qh[kk], kfl, s[n], 0, 0, 0);
        }
      }

      // ---- causal mask (diagonal tile only)
      if (t == T - 1) {
        #pragma unroll
        for (int n = 0; n < 4; ++n) {
          const int key = t * KT + n * 16 + l15;
          #pragma unroll
          for (int r = 0; r < 4; ++r) {
            if (key > qrow + 4 * g + r) s[n][r] = -INFINITY;
          }
        }
      }

      // ---- online softmax (row r lives in 16 lanes of group g at reg r)
      float rmax[4], rsum[4], scale[4];
      #pragma unroll
      for (int r = 0; r < 4; ++r)
        rmax[r] = fmaxf(fmaxf(s[0][r], s[1][r]), fmaxf(s[2][r], s[3][r]));
      #pragma unroll
      for (int mk = 1; mk <= 8; mk <<= 1) {
        #pragma unroll
        for (int r = 0; r < 4; ++r)
          rmax[r] = fmaxf(rmax[r], __shfl_xor(rmax[r], mk));
      }
      #pragma unroll
      for (int r = 0; r < 4; ++r) {
        const float mn = fmaxf(m[r], rmax[r]);
        scale[r] = __expf(m[r] - mn);  // first tile: exp(-inf)=0
        m[r] = mn;
      }
      #pragma unroll
      for (int n = 0; n < 4; ++n) {
        #pragma unroll
        for (int r = 0; r < 4; ++r) s[n][r] = __expf(s[n][r] - m[r]);
      }
      #pragma unroll
      for (int r = 0; r < 4; ++r)
        rsum[r] = (s[0][r] + s[1][r]) + (s[2][r] + s[3][r]);
      #pragma unroll
      for (int mk = 1; mk <= 8; mk <<= 1) {
        #pragma unroll
        for (int r = 0; r < 4; ++r) rsum[r] += __shfl_xor(rsum[r], mk);
      }
      #pragma unroll
      for (int r = 0; r < 4; ++r) lsum[r] = lsum[r] * scale[r] + rsum[r];
      #pragma unroll
      for (int nd = 0; nd < 4; ++nd) {
        #pragma unroll
        for (int r = 0; r < 4; ++r) o[nd][r] *= scale[r];
      }

      // ---- P -> per-wave LDS (bf16, swizzled), relayout C/D -> A-frag
      #pragma unroll
      for (int n = 0; n < 4; ++n) {
        #pragma unroll
        for (int r = 0; r < 4; ++r) {
          *reinterpret_cast<unsigned short*>(
              pw + SWZB(4 * g + r, (n * 16 + l15) * 2)) = f2bf(s[n][r]);
        }
      }
      asm volatile("s_waitcnt lgkmcnt(0)" ::: "memory");
      __builtin_amdgcn_sched_barrier(0);

      // ---- O += P V
      #pragma unroll
      for (int kblk = 0; kblk < 2; ++kblk) {
        const bf16x8 pf = *reinterpret_cast<const bf16x8*>(
            pw + SWZB(l15, kblk * 64 + g * 16));
        #pragma unroll
        for (int nd = 0; nd < 4; ++nd) {
          const bf16x8 vf = *reinterpret_cast<const bf16x8*>(
              vt + SWZB(nd * 16 + l15, kblk * 64 + g * 16));
          o[nd] = __builtin_amdgcn_mfma_f32_16x16x32_bf16(pf, vf, o[nd], 0, 0, 0);
        }
      }
    }

    // ---- epilogue: O /= l, store fp32
    float inv[4];
    #pragma unroll
    for (int r = 0; r < 4; ++r) inv[r] = 1.f / lsum[r];
    #pragma unroll
    for (int nd = 0; nd < 4; ++nd) {
      #pragma unroll
      for (int r = 0; r < 4; ++r) {
        Ob[(size_t)(qrow + 4 * g + r) * Dd + nd * 16 + l15] = o[nd][r] * inv[r];
      }
    }
  }
}

extern "C" void kernel_launch(void* const* d_in, const int* in_sizes, int n_in,
                              void* d_out, int out_size, void* d_ws, size_t ws_size,
                              hipStream_t stream) {
  const float* q = (const float*)d_in[0];
  const float* k = (const float*)d_in[1];
  const float* v = (const float*)d_in[2];
  float* o = (float*)d_out;
  const int bh_count = in_sizes[0] / (Lq * Dd);  // B*H = 32
  const int grid = bh_count * PAIRS;             // 512 blocks
  causal_attn_mfma<<<dim3((unsigned)grid), dim3(THREADS), 0, stream>>>(q, k, v, o);
  (void)d_ws; (void)ws_size; (void)n_in; (void)out_size;
}

// Round 5
// 84.436 us; speedup vs baseline: 17.4676x; 1.6749x over previous
//
#include <hip/hip_runtime.h>
#include <math.h>

// Causal attention, B=2 H=16 L=2048 D=64, fp32 in/out, scale=1.
// R5: fp16 MFMA (single-pass QK^T, error ~8x below bf16), double-buffered
// LDS with register prefetch (1 barrier/tile), b64 V-transpose staging,
// s_setprio around MFMA clusters.
// 4-wave blocks, 16 q-rows/wave, KVBLK=64, mirror-paired chunks (33 tiles).
// mfma_f32_16x16x32_f16; C/D layout col=lane&15, row=4*(lane>>4)+reg.
// LDS XOR-swizzle (row&7)<<4 on all 128B-row tiles.

typedef __attribute__((ext_vector_type(8))) _Float16 f16x8;
typedef __attribute__((ext_vector_type(4))) _Float16 f16x4;
typedef __attribute__((ext_vector_type(4))) float f32x4;

constexpr int Lq = 2048;
constexpr int Dd = 64;
constexpr int KT = 64;              // keys per LDS tile
constexpr int THREADS = 256;        // 4 waves
constexpr int CHUNK = 64;           // q rows per block chunk
constexpr int NCHUNK = Lq / CHUNK;  // 32
constexpr int PAIRS = NCHUNK / 2;   // 16

// swizzled byte offset inside a [row][128B] LDS tile
#define SWZB(row, bcol) ((((row) * 128) + (bcol)) ^ (((row) & 7) << 4))

__global__ __launch_bounds__(THREADS)
void causal_attn_mfma(const float* __restrict__ Q, const float* __restrict__ K,
                      const float* __restrict__ V, float* __restrict__ O) {
  __shared__ char ks[2][KT * 128];    // K tile [key][d] f16, swizzled (dbuf)
  __shared__ char vt[2][Dd * 128];    // V^T tile [d][key] f16, swizzled (dbuf)
  __shared__ char pl[4][16 * 128];    // per-wave P [q][key] f16, swizzled

  const int tid  = threadIdx.x;
  const int lane = tid & 63;
  const int wv   = tid >> 6;
  const int l15  = lane & 15;
  const int g    = lane >> 4;
  // V staging decomposition: thread owns keys kg*4..+3, d-chunk dq*4..+3
  const int kg = tid & 15;
  const int dq = tid >> 4;

  const int bh = blockIdx.x / PAIRS;
  const int pr = blockIdx.x % PAIRS;
  const size_t base = (size_t)bh * Lq * Dd;
  const float* Qb = Q + base;
  const float* Kb = K + base;
  const float* Vb = V + base;
  float*       Ob = O + base;
  char* pw = pl[wv];

  #pragma unroll 1
  for (int phase = 0; phase < 2; ++phase) {
    const int chunk = (phase == 0) ? pr : (NCHUNK - 1 - pr);
    const int row0  = chunk * CHUNK;
    const int T     = chunk + 1;          // key tiles for this chunk
    const int qrow  = row0 + wv * 16;     // wave's first q row

    // ---- Q fragments (A-operand): lane holds Q[qrow+l15][kk*32+g*8 .. +7]
    f16x8 qf[2];
    #pragma unroll
    for (int kk = 0; kk < 2; ++kk) {
      const float* qp = Qb + (size_t)(qrow + l15) * Dd + kk * 32 + g * 8;
      const f32x4 a = *reinterpret_cast<const f32x4*>(qp);
      const f32x4 b = *reinterpret_cast<const f32x4*>(qp + 4);
      f16x8 q8;
      #pragma unroll
      for (int i = 0; i < 4; ++i) {
        q8[i]     = (_Float16)a[i];
        q8[i + 4] = (_Float16)b[i];
      }
      qf[kk] = q8;
    }

    float m[4], lsum[4];
    f32x4 o[4];
    #pragma unroll
    for (int r = 0; r < 4; ++r) { m[r] = -INFINITY; lsum[r] = 0.f; }
    #pragma unroll
    for (int nd = 0; nd < 4; ++nd) o[nd] = f32x4{0.f, 0.f, 0.f, 0.f};

    // ---- prologue: stage tile 0 into buffer 0
    {
      f32x4 kreg[4], vreg[4];
      #pragma unroll
      for (int i = 0; i < 4; ++i) {
        const int c = tid + i * 256;
        kreg[i] = *reinterpret_cast<const f32x4*>(
            Kb + (size_t)(c >> 4) * Dd + (c & 15) * 4);
      }
      #pragma unroll
      for (int c = 0; c < 4; ++c) {
        vreg[c] = *reinterpret_cast<const f32x4*>(
            Vb + (size_t)(kg * 4 + c) * Dd + dq * 4);
      }
      __syncthreads();  // previous phase's readers done before we overwrite
      #pragma unroll
      for (int i = 0; i < 4; ++i) {
        const int c = tid + i * 256;
        f16x4 h;
        #pragma unroll
        for (int j = 0; j < 4; ++j) h[j] = (_Float16)kreg[i][j];
        *reinterpret_cast<f16x4*>(ks[0] + SWZB(c >> 4, (c & 15) * 8)) = h;
      }
      #pragma unroll
      for (int j = 0; j < 4; ++j) {  // d = dq*4+j, keys kg*4..+3
        f16x4 h;
        #pragma unroll
        for (int c = 0; c < 4; ++c) h[c] = (_Float16)vreg[c][j];
        *reinterpret_cast<f16x4*>(vt[0] + SWZB(dq * 4 + j, kg * 8)) = h;
      }
    }

    int cur = 0;
    #pragma unroll 1
    for (int t = 0; t < T; ++t) {
      __syncthreads();  // buf[cur] published; prev buf's readers done
      const char* kb = ks[cur];
      const char* vb = vt[cur];

      // ---- issue prefetch of tile t+1 (regs only; consumed after compute)
      f32x4 kreg[4], vreg[4];
      const bool pfn = (t + 1 < T);
      if (pfn) {
        const float* Kt = Kb + (size_t)(t + 1) * KT * Dd;
        const float* Vt = Vb + (size_t)(t + 1) * KT * Dd;
        #pragma unroll
        for (int i = 0; i < 4; ++i) {
          const int c = tid + i * 256;
          kreg[i] = *reinterpret_cast<const f32x4*>(
              Kt + (size_t)(c >> 4) * Dd + (c & 15) * 4);
        }
        #pragma unroll
        for (int c = 0; c < 4; ++c) {
          vreg[c] = *reinterpret_cast<const f32x4*>(
              Vt + (size_t)(kg * 4 + c) * Dd + dq * 4);
        }
      }

      // ---- S = Q K^T : 4 key-subtiles x 2 k-chunks
      f32x4 s[4];
      #pragma unroll
      for (int n = 0; n < 4; ++n) s[n] = f32x4{0.f, 0.f, 0.f, 0.f};
      __builtin_amdgcn_s_setprio(1);
      #pragma unroll
      for (int kk = 0; kk < 2; ++kk) {
        #pragma unroll
        for (int n = 0; n < 4; ++n) {
          const f16x8 kf = *reinterpret_cast<const f16x8*>(
              kb + SWZB(n * 16 + l15, kk * 64 + g * 16));
          s[n] = __builtin_amdgcn_mfma_f32_16x16x32_f16(qf[kk], kf, s[n], 0, 0, 0);
        }
      }
      __builtin_amdgcn_s_setprio(0);

      // ---- causal mask (diagonal tile only)
      if (t == T - 1) {
        #pragma unroll
        for (int n = 0; n < 4; ++n) {
          const int key = t * KT + n * 16 + l15;
          #pragma unroll
          for (int r = 0; r < 4; ++r) {
            if (key > qrow + 4 * g + r) s[n][r] = -INFINITY;
          }
        }
      }

      // ---- online softmax (row r lives in 16 lanes of group g at reg r)
      float rmax[4], rsum[4], scale[4];
      #pragma unroll
      for (int r = 0; r < 4; ++r)
        rmax[r] = fmaxf(fmaxf(s[0][r], s[1][r]), fmaxf(s[2][r], s[3][r]));
      #pragma unroll
      for (int mk = 1; mk <= 8; mk <<= 1) {
        #pragma unroll
        for (int r = 0; r < 4; ++r)
          rmax[r] = fmaxf(rmax[r], __shfl_xor(rmax[r], mk));
      }
      #pragma unroll
      for (int r = 0; r < 4; ++r) {
        const float mn = fmaxf(m[r], rmax[r]);
        scale[r] = __expf(m[r] - mn);  // first tile: exp(-inf)=0
        m[r] = mn;
      }
      #pragma unroll
      for (int n = 0; n < 4; ++n) {
        #pragma unroll
        for (int r = 0; r < 4; ++r) s[n][r] = __expf(s[n][r] - m[r]);
      }
      #pragma unroll
      for (int r = 0; r < 4; ++r)
        rsum[r] = (s[0][r] + s[1][r]) + (s[2][r] + s[3][r]);
      #pragma unroll
      for (int mk = 1; mk <= 8; mk <<= 1) {
        #pragma unroll
        for (int r = 0; r < 4; ++r) rsum[r] += __shfl_xor(rsum[r], mk);
      }
      #pragma unroll
      for (int r = 0; r < 4; ++r) lsum[r] = lsum[r] * scale[r] + rsum[r];
      #pragma unroll
      for (int nd = 0; nd < 4; ++nd) {
        #pragma unroll
        for (int r = 0; r < 4; ++r) o[nd][r] *= scale[r];
      }

      // ---- P -> per-wave LDS (f16, swizzled), relayout C/D -> A-frag
      #pragma unroll
      for (int n = 0; n < 4; ++n) {
        #pragma unroll
        for (int r = 0; r < 4; ++r) {
          *reinterpret_cast<_Float16*>(
              pw + SWZB(4 * g + r, (n * 16 + l15) * 2)) = (_Float16)s[n][r];
        }
      }
      asm volatile("s_waitcnt lgkmcnt(0)" ::: "memory");
      __builtin_amdgcn_sched_barrier(0);

      // ---- O += P V
      __builtin_amdgcn_s_setprio(1);
      #pragma unroll
      for (int kblk = 0; kblk < 2; ++kblk) {
        const f16x8 pf = *reinterpret_cast<const f16x8*>(
            pw + SWZB(l15, kblk * 64 + g * 16));
        #pragma unroll
        for (int nd = 0; nd < 4; ++nd) {
          const f16x8 vf = *reinterpret_cast<const f16x8*>(
              vb + SWZB(nd * 16 + l15, kblk * 64 + g * 16));
          o[nd] = __builtin_amdgcn_mfma_f32_16x16x32_f16(pf, vf, o[nd], 0, 0, 0);
        }
      }
      __builtin_amdgcn_s_setprio(0);

      // ---- write prefetched tile into the other buffer
      if (pfn) {
        char* kn = ks[cur ^ 1];
        char* vn = vt[cur ^ 1];
        #pragma unroll
        for (int i = 0; i < 4; ++i) {
          const int c = tid + i * 256;
          f16x4 h;
          #pragma unroll
          for (int j = 0; j < 4; ++j) h[j] = (_Float16)kreg[i][j];
          *reinterpret_cast<f16x4*>(kn + SWZB(c >> 4, (c & 15) * 8)) = h;
        }
        #pragma unroll
        for (int j = 0; j < 4; ++j) {
          f16x4 h;
          #pragma unroll
          for (int c = 0; c < 4; ++c) h[c] = (_Float16)vreg[c][j];
          *reinterpret_cast<f16x4*>(vn + SWZB(dq * 4 + j, kg * 8)) = h;
        }
      }
      cur ^= 1;
    }

    // ---- epilogue: O /= l, store fp32
    float inv[4];
    #pragma unroll
    for (int r = 0; r < 4; ++r) inv[r] = 1.f / lsum[r];
    #pragma unroll
    for (int nd = 0; nd < 4; ++nd) {
      #pragma unroll
      for (int r = 0; r < 4; ++r) {
        Ob[(size_t)(qrow + 4 * g + r) * Dd + nd * 16 + l15] = o[nd][r] * inv[r];
      }
    }
  }
}

extern "C" void kernel_launch(void* const* d_in, const int* in_sizes, int n_in,
                              void* d_out, int out_size, void* d_ws, size_t ws_size,
                              hipStream_t stream) {
  const float* q = (const float*)d_in[0];
  const float* k = (const float*)d_in[1];
  const float* v = (const float*)d_in[2];
  float* o = (float*)d_out;
  const int bh_count = in_sizes[0] / (Lq * Dd);  // B*H = 32
  const int grid = bh_count * PAIRS;             // 512 blocks
  causal_attn_mfma<<<dim3((unsigned)grid), dim3(THREADS), 0, stream>>>(q, k, v, o);
  (void)d_ws; (void)ws_size; (void)n_in; (void)out_size;
}

// Round 6
// 84.190 us; speedup vs baseline: 17.5187x; 1.0029x over previous
//
#include <hip/hip_runtime.h>
#include <math.h>

// Causal attention, B=2 H=16 L=2048 D=64, fp32 in/out, scale=1.
// R6: prepass converts K->f16 and V->f16-transposed into d_ws; main kernel
// stages K/VT tiles via global_load_lds (width 16) with pre-swizzled global
// source addresses (LDS stays linear-dest, reads use XOR swizzle).
// Main: 8-wave blocks (512 thr), CHUNK=128 q-rows, KVBLK=64, mirror-paired
// chunks (34 tiles/block), mfma_f32_16x16x32_f16, per-wave in-LDS P relayout.
// Fallback (ws too small): R5 kernel (84us).

typedef __attribute__((ext_vector_type(8))) _Float16 f16x8;
typedef __attribute__((ext_vector_type(4))) _Float16 f16x4;
typedef __attribute__((ext_vector_type(4))) float f32x4;
typedef unsigned short u16;
typedef __attribute__((ext_vector_type(8))) u16 u16x8;

constexpr int Lq = 2048;
constexpr int Dd = 64;
constexpr int KT = 64;
constexpr int BH = 32;

// swizzled byte offset inside a [row][128B] LDS tile
#define SWZB(row, bcol) ((((row) * 128) + (bcol)) ^ (((row) & 7) << 4))

#define GLOAD_LDS16(g, l)                                                     \
  __builtin_amdgcn_global_load_lds(                                           \
      (const __attribute__((address_space(1))) void*)(g),                     \
      (__attribute__((address_space(3))) void*)(l), 16, 0, 0)

static __device__ __forceinline__ u16 f2h(float x) {
  return __builtin_bit_cast(u16, (_Float16)x);
}

// ============================ prepass =====================================
// blocks [0, 1024): K fp32 -> f16 flat (16 elems/thread)
// blocks [1024, 2048): V -> VT f16 [h][d][key], 64x64 tile transpose via LDS
constexpr int PREP_KB = (BH * Lq * Dd) / (256 * 16);  // 1024

__global__ __launch_bounds__(256)
void attn_prep(const float* __restrict__ K, const float* __restrict__ V,
               u16* __restrict__ Kh, u16* __restrict__ VTh) {
  const int b = blockIdx.x;
  const int tid = threadIdx.x;
  if (b < PREP_KB) {
    const size_t base = ((size_t)b * 256 + tid) * 16;
    const f32x4* src = reinterpret_cast<const f32x4*>(K + base);
    u16x8 o0, o1;
    #pragma unroll
    for (int i = 0; i < 2; ++i) {
      const f32x4 a = src[i];
      #pragma unroll
      for (int j = 0; j < 4; ++j) o0[i * 4 + j] = f2h(a[j]);
    }
    #pragma unroll
    for (int i = 0; i < 2; ++i) {
      const f32x4 a = src[2 + i];
      #pragma unroll
      for (int j = 0; j < 4; ++j) o1[i * 4 + j] = f2h(a[j]);
    }
    *reinterpret_cast<u16x8*>(Kh + base) = o0;
    *reinterpret_cast<u16x8*>(Kh + base + 8) = o1;
  } else {
    __shared__ u16 lt[64][66];  // pad 2 -> 33-dword row stride, conflict-free
    const int vb = b - PREP_KB;
    const int h = vb >> 5, tt = vb & 31;
    const float* Vt = V + ((size_t)h * Lq + tt * 64) * Dd;
    const int r = tid & 63, dg = tid >> 6;  // row, d-group(16)
    #pragma unroll
    for (int i = 0; i < 4; ++i) {
      const f32x4 a = *reinterpret_cast<const f32x4*>(Vt + (size_t)r * Dd + dg * 16 + i * 4);
      #pragma unroll
      for (int j = 0; j < 2; ++j) {
        const unsigned two =
            (unsigned)f2h(a[2 * j]) | ((unsigned)f2h(a[2 * j + 1]) << 16);
        *reinterpret_cast<unsigned*>(&lt[r][dg * 16 + i * 4 + j * 2]) = two;
      }
    }
    __syncthreads();
    const int d = tid >> 2, kq = tid & 3;
    u16x8 w0, w1;
    #pragma unroll
    for (int j = 0; j < 8; ++j) w0[j] = lt[kq * 16 + j][d];
    #pragma unroll
    for (int j = 0; j < 8; ++j) w1[j] = lt[kq * 16 + 8 + j][d];
    u16* dst = VTh + ((size_t)h * Dd + d) * Lq + tt * 64 + kq * 16;
    *reinterpret_cast<u16x8*>(dst) = w0;
    *reinterpret_cast<u16x8*>(dst + 8) = w1;
  }
}

// ============================ main kernel =================================
constexpr int THREADS = 512;          // 8 waves
constexpr int CHUNK = 128;
constexpr int NCHUNK = Lq / CHUNK;    // 16
constexpr int PAIRS = NCHUNK / 2;     // 8

__global__ __launch_bounds__(THREADS)
void attn_main(const float* __restrict__ Q, float* __restrict__ O,
               const u16* __restrict__ Kh, const u16* __restrict__ VTh) {
  __shared__ char ks[2][8192];   // K tile [key][d] f16, swizzled, dbuf
  __shared__ char vt2[2][8192];  // VT tile [d][key] f16, swizzled, dbuf
  __shared__ char pl[8][2048];   // per-wave P [q 16][key 64] f16, swizzled

  const int tid  = threadIdx.x;
  const int lane = tid & 63;
  const int wv   = tid >> 6;   // 0..7
  const int l15  = lane & 15;
  const int g    = lane >> 4;

  const int bh = blockIdx.x / PAIRS;
  const int pr = blockIdx.x % PAIRS;
  const float* Qb = Q + (size_t)bh * Lq * Dd;
  float*       Ob = O + (size_t)bh * Lq * Dd;
  const u16*   Kb = Kh + (size_t)bh * Lq * Dd;
  const u16*   Vb = VTh + (size_t)bh * Dd * Lq;
  char* pw = pl[wv];

  // pre-swizzled source slot: LDS slot `lane` receives global slot lsw
  const int lsw = lane ^ ((lane >> 3) & 7);
  const int r_ = lsw >> 3, s_ = lsw & 7;  // VT chunk: row-in-chunk, 16B slot

  #pragma unroll 1
  for (int phase = 0; phase < 2; ++phase) {
    const int chunk = (phase == 0) ? pr : (NCHUNK - 1 - pr);
    const int row0  = chunk * CHUNK;
    const int T     = 2 * (chunk + 1);
    const int qrow  = row0 + wv * 16;
    const int tLast = qrow >> 6;  // wave's diagonal tile

    // ---- Q fragments: lane holds Q[qrow+l15][kk*32+g*8 .. +7] (f16)
    f16x8 qf[2];
    #pragma unroll
    for (int kk = 0; kk < 2; ++kk) {
      const float* qp = Qb + (size_t)(qrow + l15) * Dd + kk * 32 + g * 8;
      const f32x4 a = *reinterpret_cast<const f32x4*>(qp);
      const f32x4 b = *reinterpret_cast<const f32x4*>(qp + 4);
      f16x8 q8;
      #pragma unroll
      for (int i = 0; i < 4; ++i) {
        q8[i]     = (_Float16)a[i];
        q8[i + 4] = (_Float16)b[i];
      }
      qf[kk] = q8;
    }

    float m[4], lsum[4];
    f32x4 o[4];
    #pragma unroll
    for (int r = 0; r < 4; ++r) { m[r] = -INFINITY; lsum[r] = 0.f; }
    #pragma unroll
    for (int nd = 0; nd < 4; ++nd) o[nd] = f32x4{0.f, 0.f, 0.f, 0.f};

    __syncthreads();  // previous phase's LDS readers done
    // ---- issue tile 0 DMA into buf 0 (wave wv stages rows 8wv..8wv+7)
    GLOAD_LDS16(Kb + (size_t)(8 * wv) * Dd + lsw * 8, ks[0] + wv * 1024);
    GLOAD_LDS16(Vb + (size_t)(8 * wv + r_) * Lq + s_ * 8, vt2[0] + wv * 1024);

    int cur = 0;
    #pragma unroll 1
    for (int t = 0; t < T; ++t) {
      __syncthreads();  // drains DMA: tile t resident in buf[cur]
      if (t + 1 < T) {  // prefetch next tile into other buffer
        GLOAD_LDS16(Kb + (size_t)((t + 1) * KT + 8 * wv) * Dd + lsw * 8,
                    ks[cur ^ 1] + wv * 1024);
        GLOAD_LDS16(Vb + (size_t)(8 * wv + r_) * Lq + (t + 1) * KT + s_ * 8,
                    vt2[cur ^ 1] + wv * 1024);
      }
      if (t <= tLast) {  // wave-uniform: skip tiles past this wave's diagonal
        const char* kb = ks[cur];
        const char* vb = vt2[cur];

        // ---- S = Q K^T
        f32x4 s[4];
        #pragma unroll
        for (int n = 0; n < 4; ++n) s[n] = f32x4{0.f, 0.f, 0.f, 0.f};
        __builtin_amdgcn_s_setprio(1);
        #pragma unroll
        for (int kk = 0; kk < 2; ++kk) {
          #pragma unroll
          for (int n = 0; n < 4; ++n) {
            const f16x8 kf = *reinterpret_cast<const f16x8*>(
                kb + SWZB(n * 16 + l15, kk * 64 + g * 16));
            s[n] = __builtin_amdgcn_mfma_f32_16x16x32_f16(qf[kk], kf, s[n], 0, 0, 0);
          }
        }
        __builtin_amdgcn_s_setprio(0);

        // ---- causal mask on the diagonal tile
        if (t == tLast) {
          #pragma unroll
          for (int n = 0; n < 4; ++n) {
            const int key = t * KT + n * 16 + l15;
            #pragma unroll
            for (int r = 0; r < 4; ++r) {
              if (key > qrow + 4 * g + r) s[n][r] = -INFINITY;
            }
          }
        }

        // ---- online softmax (row r in 16 lanes of group g, reg r)
        float rmax[4], rsum[4], scale[4];
        #pragma unroll
        for (int r = 0; r < 4; ++r)
          rmax[r] = fmaxf(fmaxf(s[0][r], s[1][r]), fmaxf(s[2][r], s[3][r]));
        #pragma unroll
        for (int mk = 1; mk <= 8; mk <<= 1) {
          #pragma unroll
          for (int r = 0; r < 4; ++r)
            rmax[r] = fmaxf(rmax[r], __shfl_xor(rmax[r], mk));
        }
        #pragma unroll
        for (int r = 0; r < 4; ++r) {
          const float mn = fmaxf(m[r], rmax[r]);
          scale[r] = __expf(m[r] - mn);  // first tile: exp(-inf)=0
          m[r] = mn;
        }
        #pragma unroll
        for (int n = 0; n < 4; ++n) {
          #pragma unroll
          for (int r = 0; r < 4; ++r) s[n][r] = __expf(s[n][r] - m[r]);
        }
        #pragma unroll
        for (int r = 0; r < 4; ++r)
          rsum[r] = (s[0][r] + s[1][r]) + (s[2][r] + s[3][r]);
        #pragma unroll
        for (int mk = 1; mk <= 8; mk <<= 1) {
          #pragma unroll
          for (int r = 0; r < 4; ++r) rsum[r] += __shfl_xor(rsum[r], mk);
        }
        #pragma unroll
        for (int r = 0; r < 4; ++r) lsum[r] = lsum[r] * scale[r] + rsum[r];
        #pragma unroll
        for (int nd = 0; nd < 4; ++nd) {
          #pragma unroll
          for (int r = 0; r < 4; ++r) o[nd][r] *= scale[r];
        }

        // ---- P -> per-wave LDS (f16, swizzled): C/D -> A-frag relayout
        #pragma unroll
        for (int n = 0; n < 4; ++n) {
          #pragma unroll
          for (int r = 0; r < 4; ++r) {
            *reinterpret_cast<_Float16*>(
                pw + SWZB(4 * g + r, (n * 16 + l15) * 2)) = (_Float16)s[n][r];
          }
        }
        asm volatile("s_waitcnt lgkmcnt(0)" ::: "memory");
        __builtin_amdgcn_sched_barrier(0);

        // ---- O += P V
        __builtin_amdgcn_s_setprio(1);
        #pragma unroll
        for (int kblk = 0; kblk < 2; ++kblk) {
          const f16x8 pf = *reinterpret_cast<const f16x8*>(
              pw + SWZB(l15, kblk * 64 + g * 16));
          #pragma unroll
          for (int nd = 0; nd < 4; ++nd) {
            const f16x8 vf = *reinterpret_cast<const f16x8*>(
                vb + SWZB(nd * 16 + l15, kblk * 64 + g * 16));
            o[nd] = __builtin_amdgcn_mfma_f32_16x16x32_f16(pf, vf, o[nd], 0, 0, 0);
          }
        }
        __builtin_amdgcn_s_setprio(0);
      }
      cur ^= 1;
    }

    // ---- epilogue: O /= l, store fp32
    float inv[4];
    #pragma unroll
    for (int r = 0; r < 4; ++r) inv[r] = 1.f / lsum[r];
    #pragma unroll
    for (int nd = 0; nd < 4; ++nd) {
      #pragma unroll
      for (int r = 0; r < 4; ++r) {
        Ob[(size_t)(qrow + 4 * g + r) * Dd + nd * 16 + l15] = o[nd][r] * inv[r];
      }
    }
  }
}

// ======================= fallback (R5, no ws needed) ======================
__global__ __launch_bounds__(256)
void causal_attn_fb(const float* __restrict__ Q, const float* __restrict__ K,
                    const float* __restrict__ V, float* __restrict__ O) {
  __shared__ char ks[2][KT * 128];
  __shared__ char vt[2][Dd * 128];
  __shared__ char pl[4][16 * 128];
  const int tid = threadIdx.x, lane = tid & 63, wv = tid >> 6;
  const int l15 = lane & 15, g = lane >> 4;
  const int kg = tid & 15, dq = tid >> 4;
  const int bh = blockIdx.x / 16, pr = blockIdx.x % 16;
  const size_t base = (size_t)bh * Lq * Dd;
  const float* Qb = Q + base; const float* Kb = K + base;
  const float* Vb = V + base; float* Ob = O + base;
  char* pw = pl[wv];
  #pragma unroll 1
  for (int phase = 0; phase < 2; ++phase) {
    const int chunk = (phase == 0) ? pr : (31 - pr);
    const int row0 = chunk * 64, T = chunk + 1, qrow = row0 + wv * 16;
    f16x8 qf[2];
    #pragma unroll
    for (int kk = 0; kk < 2; ++kk) {
      const float* qp = Qb + (size_t)(qrow + l15) * Dd + kk * 32 + g * 8;
      const f32x4 a = *reinterpret_cast<const f32x4*>(qp);
      const f32x4 b = *reinterpret_cast<const f32x4*>(qp + 4);
      f16x8 q8;
      #pragma unroll
      for (int i = 0; i < 4; ++i) { q8[i] = (_Float16)a[i]; q8[i+4] = (_Float16)b[i]; }
      qf[kk] = q8;
    }
    float m[4], lsum[4]; f32x4 o[4];
    #pragma unroll
    for (int r = 0; r < 4; ++r) { m[r] = -INFINITY; lsum[r] = 0.f; }
    #pragma unroll
    for (int nd = 0; nd < 4; ++nd) o[nd] = f32x4{0.f, 0.f, 0.f, 0.f};
    {
      f32x4 kreg[4], vreg[4];
      #pragma unroll
      for (int i = 0; i < 4; ++i) {
        const int c = tid + i * 256;
        kreg[i] = *reinterpret_cast<const f32x4*>(Kb + (size_t)(c >> 4) * Dd + (c & 15) * 4);
      }
      #pragma unroll
      for (int c = 0; c < 4; ++c)
        vreg[c] = *reinterpret_cast<const f32x4*>(Vb + (size_t)(kg * 4 + c) * Dd + dq * 4);
      __syncthreads();
      #pragma unroll
      for (int i = 0; i < 4; ++i) {
        const int c = tid + i * 256;
        f16x4 h;
        #pragma unroll
        for (int j = 0; j < 4; ++j) h[j] = (_Float16)kreg[i][j];
        *reinterpret_cast<f16x4*>(ks[0] + SWZB(c >> 4, (c & 15) * 8)) = h;
      }
      #pragma unroll
      for (int j = 0; j < 4; ++j) {
        f16x4 h;
        #pragma unroll
        for (int c = 0; c < 4; ++c) h[c] = (_Float16)vreg[c][j];
        *reinterpret_cast<f16x4*>(vt[0] + SWZB(dq * 4 + j, kg * 8)) = h;
      }
    }
    int cur = 0;
    #pragma unroll 1
    for (int t = 0; t < T; ++t) {
      __syncthreads();
      const char* kb = ks[cur]; const char* vb = vt[cur];
      f32x4 kreg[4], vreg[4];
      const bool pfn = (t + 1 < T);
      if (pfn) {
        const float* Kt = Kb + (size_t)(t + 1) * KT * Dd;
        const float* Vt = Vb + (size_t)(t + 1) * KT * Dd;
        #pragma unroll
        for (int i = 0; i < 4; ++i) {
          const int c = tid + i * 256;
          kreg[i] = *reinterpret_cast<const f32x4*>(Kt + (size_t)(c >> 4) * Dd + (c & 15) * 4);
        }
        #pragma unroll
        for (int c = 0; c < 4; ++c)
          vreg[c] = *reinterpret_cast<const f32x4*>(Vt + (size_t)(kg * 4 + c) * Dd + dq * 4);
      }
      f32x4 s[4];
      #pragma unroll
      for (int n = 0; n < 4; ++n) s[n] = f32x4{0.f, 0.f, 0.f, 0.f};
      #pragma unroll
      for (int kk = 0; kk < 2; ++kk) {
        #pragma unroll
        for (int n = 0; n < 4; ++n) {
          const f16x8 kf = *reinterpret_cast<const f16x8*>(kb + SWZB(n * 16 + l15, kk * 64 + g * 16));
          s[n] = __builtin_amdgcn_mfma_f32_16x16x32_f16(qf[kk], kf, s[n], 0, 0, 0);
        }
      }
      if (t == T - 1) {
        #pragma unroll
        for (int n = 0; n < 4; ++n) {
          const int key = t * KT + n * 16 + l15;
          #pragma unroll
          for (int r = 0; r < 4; ++r)
            if (key > qrow + 4 * g + r) s[n][r] = -INFINITY;
        }
      }
      float rmax[4], rsum[4], scale[4];
      #pragma unroll
      for (int r = 0; r < 4; ++r)
        rmax[r] = fmaxf(fmaxf(s[0][r], s[1][r]), fmaxf(s[2][r], s[3][r]));
      #pragma unroll
      for (int mk = 1; mk <= 8; mk <<= 1) {
        #pragma unroll
        for (int r = 0; r < 4; ++r) rmax[r] = fmaxf(rmax[r], __shfl_xor(rmax[r], mk));
      }
      #pragma unroll
      for (int r = 0; r < 4; ++r) {
        const float mn = fmaxf(m[r], rmax[r]);
        scale[r] = __expf(m[r] - mn); m[r] = mn;
      }
      #pragma unroll
      for (int n = 0; n < 4; ++n) {
        #pragma unroll
        for (int r = 0; r < 4; ++r) s[n][r] = __expf(s[n][r] - m[r]);
      }
      #pragma unroll
      for (int r = 0; r < 4; ++r) rsum[r] = (s[0][r] + s[1][r]) + (s[2][r] + s[3][r]);
      #pragma unroll
      for (int mk = 1; mk <= 8; mk <<= 1) {
        #pragma unroll
        for (int r = 0; r < 4; ++r) rsum[r] += __shfl_xor(rsum[r], mk);
      }
      #pragma unroll
      for (int r = 0; r < 4; ++r) lsum[r] = lsum[r] * scale[r] + rsum[r];
      #pragma unroll
      for (int nd = 0; nd < 4; ++nd) {
        #pragma unroll
        for (int r = 0; r < 4; ++r) o[nd][r] *= scale[r];
      }
      #pragma unroll
      for (int n = 0; n < 4; ++n) {
        #pragma unroll
        for (int r = 0; r < 4; ++r)
          *reinterpret_cast<_Float16*>(pw + SWZB(4 * g + r, (n * 16 + l15) * 2)) = (_Float16)s[n][r];
      }
      asm volatile("s_waitcnt lgkmcnt(0)" ::: "memory");
      __builtin_amdgcn_sched_barrier(0);
      #pragma unroll
      for (int kblk = 0; kblk < 2; ++kblk) {
        const f16x8 pf = *reinterpret_cast<const f16x8*>(pw + SWZB(l15, kblk * 64 + g * 16));
        #pragma unroll
        for (int nd = 0; nd < 4; ++nd) {
          const f16x8 vf = *reinterpret_cast<const f16x8*>(vb + SWZB(nd * 16 + l15, kblk * 64 + g * 16));
          o[nd] = __builtin_amdgcn_mfma_f32_16x16x32_f16(pf, vf, o[nd], 0, 0, 0);
        }
      }
      if (pfn) {
        char* kn = ks[cur ^ 1]; char* vn = vt[cur ^ 1];
        #pragma unroll
        for (int i = 0; i < 4; ++i) {
          const int c = tid + i * 256;
          f16x4 h;
          #pragma unroll
          for (int j = 0; j < 4; ++j) h[j] = (_Float16)kreg[i][j];
          *reinterpret_cast<f16x4*>(kn + SWZB(c >> 4, (c & 15) * 8)) = h;
        }
        #pragma unroll
        for (int j = 0; j < 4; ++j) {
          f16x4 h;
          #pragma unroll
          for (int c = 0; c < 4; ++c) h[c] = (_Float16)vreg[c][j];
          *reinterpret_cast<f16x4*>(vn + SWZB(dq * 4 + j, kg * 8)) = h;
        }
      }
      cur ^= 1;
    }
    float inv[4];
    #pragma unroll
    for (int r = 0; r < 4; ++r) inv[r] = 1.f / lsum[r];
    #pragma unroll
    for (int nd = 0; nd < 4; ++nd) {
      #pragma unroll
      for (int r = 0; r < 4; ++r)
        Ob[(size_t)(qrow + 4 * g + r) * Dd + nd * 16 + l15] = o[nd][r] * inv[r];
    }
  }
}

extern "C" void kernel_launch(void* const* d_in, const int* in_sizes, int n_in,
                              void* d_out, int out_size, void* d_ws, size_t ws_size,
                              hipStream_t stream) {
  const float* q = (const float*)d_in[0];
  const float* k = (const float*)d_in[1];
  const float* v = (const float*)d_in[2];
  float* o = (float*)d_out;
  const size_t elems = (size_t)BH * Lq * Dd;
  const size_t need = elems * 2 * 2;  // Kh + VTh, f16
  if (ws_size >= need) {
    u16* Kh = (u16*)d_ws;
    u16* VTh = Kh + elems;
    attn_prep<<<dim3(2 * PREP_KB), dim3(256), 0, stream>>>(k, v, Kh, VTh);
    attn_main<<<dim3(BH * PAIRS), dim3(THREADS), 0, stream>>>(q, o, Kh, VTh);
  } else {
    causal_attn_fb<<<dim3(BH * 16), dim3(256), 0, stream>>>(q, k, v, o);
  }
  (void)in_sizes; (void)n_in; (void)out_size;
}

// Round 7
// 81.525 us; speedup vs baseline: 18.0913x; 1.0327x over previous
//
#include <hip/hip_runtime.h>
#include <math.h>

// Causal attention, B=2 H=16 L=2048 D=64, fp32 in/out, scale=1.
// R7: prepass (K->f16, V->f16 transposed) into d_ws; main kernel stages
// K/VT via global_load_lds(16) with pre-swizzled global source.
// Main: 4-wave blocks (256 thr), CHUNK=64 q-rows, KVBLK=64, mirror-paired
// chunks (33 tiles/block), grid 512 = 2 blocks/CU (4 waves/SIMD),
// XCD-swizzled blockIdx (T1), defer-max online softmax (T13, THR=8).
// mfma_f32_16x16x32_f16; C/D layout col=lane&15, row=4*(lane>>4)+reg.
// LDS XOR-swizzle (row&7)<<4 on all 128B-row tiles.
// Fallback (ws too small): R5 kernel.

typedef __attribute__((ext_vector_type(8))) _Float16 f16x8;
typedef __attribute__((ext_vector_type(4))) _Float16 f16x4;
typedef __attribute__((ext_vector_type(4))) float f32x4;
typedef unsigned short u16;
typedef __attribute__((ext_vector_type(8))) u16 u16x8;

constexpr int Lq = 2048;
constexpr int Dd = 64;
constexpr int KT = 64;
constexpr int BH = 32;

// swizzled byte offset inside a [row][128B] LDS tile
#define SWZB(row, bcol) ((((row) * 128) + (bcol)) ^ (((row) & 7) << 4))

#define GLOAD_LDS16(g, l)                                                     \
  __builtin_amdgcn_global_load_lds(                                           \
      (const __attribute__((address_space(1))) void*)(g),                     \
      (__attribute__((address_space(3))) void*)(l), 16, 0, 0)

static __device__ __forceinline__ u16 f2h(float x) {
  return __builtin_bit_cast(u16, (_Float16)x);
}

// ============================ prepass =====================================
// blocks [0, 1024): K fp32 -> f16 flat (16 elems/thread)
// blocks [1024, 2048): V -> VT f16 [h][d][key], 64x64 tile transpose via LDS
constexpr int PREP_KB = (BH * Lq * Dd) / (256 * 16);  // 1024

__global__ __launch_bounds__(256)
void attn_prep(const float* __restrict__ K, const float* __restrict__ V,
               u16* __restrict__ Kh, u16* __restrict__ VTh) {
  const int b = blockIdx.x;
  const int tid = threadIdx.x;
  if (b < PREP_KB) {
    const size_t base = ((size_t)b * 256 + tid) * 16;
    const f32x4* src = reinterpret_cast<const f32x4*>(K + base);
    u16x8 o0, o1;
    #pragma unroll
    for (int i = 0; i < 2; ++i) {
      const f32x4 a = src[i];
      #pragma unroll
      for (int j = 0; j < 4; ++j) o0[i * 4 + j] = f2h(a[j]);
    }
    #pragma unroll
    for (int i = 0; i < 2; ++i) {
      const f32x4 a = src[2 + i];
      #pragma unroll
      for (int j = 0; j < 4; ++j) o1[i * 4 + j] = f2h(a[j]);
    }
    *reinterpret_cast<u16x8*>(Kh + base) = o0;
    *reinterpret_cast<u16x8*>(Kh + base + 8) = o1;
  } else {
    __shared__ u16 lt[64][66];  // +2 pad -> conflict-free transpose
    const int vb = b - PREP_KB;
    const int h = vb >> 5, tt = vb & 31;
    const float* Vt = V + ((size_t)h * Lq + tt * 64) * Dd;
    const int r = tid & 63, dg = tid >> 6;
    #pragma unroll
    for (int i = 0; i < 4; ++i) {
      const f32x4 a = *reinterpret_cast<const f32x4*>(Vt + (size_t)r * Dd + dg * 16 + i * 4);
      #pragma unroll
      for (int j = 0; j < 2; ++j) {
        const unsigned two =
            (unsigned)f2h(a[2 * j]) | ((unsigned)f2h(a[2 * j + 1]) << 16);
        *reinterpret_cast<unsigned*>(&lt[r][dg * 16 + i * 4 + j * 2]) = two;
      }
    }
    __syncthreads();
    const int d = tid >> 2, kq = tid & 3;
    u16x8 w0, w1;
    #pragma unroll
    for (int j = 0; j < 8; ++j) w0[j] = lt[kq * 16 + j][d];
    #pragma unroll
    for (int j = 0; j < 8; ++j) w1[j] = lt[kq * 16 + 8 + j][d];
    u16* dst = VTh + ((size_t)h * Dd + d) * Lq + tt * 64 + kq * 16;
    *reinterpret_cast<u16x8*>(dst) = w0;
    *reinterpret_cast<u16x8*>(dst + 8) = w1;
  }
}

// ============================ main kernel =================================
constexpr int THREADS = 256;          // 4 waves
constexpr int CHUNK = 64;
constexpr int NCHUNK = Lq / CHUNK;    // 32
constexpr int PAIRS = NCHUNK / 2;     // 16

__global__ __launch_bounds__(THREADS)
void attn_main(const float* __restrict__ Q, float* __restrict__ O,
               const u16* __restrict__ Kh, const u16* __restrict__ VTh) {
  __shared__ char ks[2][8192];   // K tile [key][d] f16, swizzled, dbuf
  __shared__ char vt2[2][8192];  // VT tile [d][key] f16, swizzled, dbuf
  __shared__ char pl[4][2048];   // per-wave P [q 16][key 64] f16, swizzled

  const int tid  = threadIdx.x;
  const int lane = tid & 63;
  const int wv   = tid >> 6;   // 0..3
  const int l15  = lane & 15;
  const int g    = lane >> 4;

  // T1: XCD-aware swizzle (grid 512, 512%8==0 -> bijective).
  // XCD x gets 64 consecutive work units = 4 heads (2MB f16 KV in 4MB L2).
  const int bid = blockIdx.x;
  const int swz = (bid & 7) * 64 + (bid >> 3);
  const int bh = swz / PAIRS;
  const int pr = swz % PAIRS;

  const float* Qb = Q + (size_t)bh * Lq * Dd;
  float*       Ob = O + (size_t)bh * Lq * Dd;
  const u16*   Kb = Kh + (size_t)bh * Lq * Dd;
  const u16*   Vb = VTh + (size_t)bh * Dd * Lq;
  char* pw = pl[wv];

  // pre-swizzled source slot: LDS 16B-slot `lane` receives global slot lsw
  const int lsw = lane ^ ((lane >> 3) & 7);
  const int r_ = lsw >> 3, s_ = lsw & 7;

  #pragma unroll 1
  for (int phase = 0; phase < 2; ++phase) {
    const int chunk = (phase == 0) ? pr : (NCHUNK - 1 - pr);
    const int row0  = chunk * CHUNK;
    const int T     = chunk + 1;          // key tiles (diagonal tile = last)
    const int qrow  = row0 + wv * 16;

    // ---- Q fragments: lane holds Q[qrow+l15][kk*32+g*8 .. +7] (f16)
    f16x8 qf[2];
    #pragma unroll
    for (int kk = 0; kk < 2; ++kk) {
      const float* qp = Qb + (size_t)(qrow + l15) * Dd + kk * 32 + g * 8;
      const f32x4 a = *reinterpret_cast<const f32x4*>(qp);
      const f32x4 b = *reinterpret_cast<const f32x4*>(qp + 4);
      f16x8 q8;
      #pragma unroll
      for (int i = 0; i < 4; ++i) {
        q8[i]     = (_Float16)a[i];
        q8[i + 4] = (_Float16)b[i];
      }
      qf[kk] = q8;
    }

    float m[4], lsum[4];
    f32x4 o[4];
    #pragma unroll
    for (int r = 0; r < 4; ++r) { m[r] = -INFINITY; lsum[r] = 0.f; }
    #pragma unroll
    for (int nd = 0; nd < 4; ++nd) o[nd] = f32x4{0.f, 0.f, 0.f, 0.f};

    __syncthreads();  // previous phase's LDS readers done
    // ---- tile 0 DMA into buf 0: wave wv stages rows 16wv..16wv+15
    #pragma unroll
    for (int i = 0; i < 2; ++i) {
      GLOAD_LDS16(Kb + (size_t)(16 * wv + 8 * i + r_) * Dd + s_ * 8,
                  ks[0] + wv * 2048 + i * 1024);
      GLOAD_LDS16(Vb + (size_t)(16 * wv + 8 * i + r_) * Lq + s_ * 8,
                  vt2[0] + wv * 2048 + i * 1024);
    }

    int cur = 0;
    #pragma unroll 1
    for (int t = 0; t < T; ++t) {
      __syncthreads();  // drains DMA: tile t resident in buf[cur]
      if (t + 1 < T) {  // prefetch next tile into other buffer
        #pragma unroll
        for (int i = 0; i < 2; ++i) {
          GLOAD_LDS16(Kb + (size_t)((t + 1) * KT + 16 * wv + 8 * i + r_) * Dd + s_ * 8,
                      ks[cur ^ 1] + wv * 2048 + i * 1024);
          GLOAD_LDS16(Vb + (size_t)(16 * wv + 8 * i + r_) * Lq + (t + 1) * KT + s_ * 8,
                      vt2[cur ^ 1] + wv * 2048 + i * 1024);
        }
      }
      const char* kb = ks[cur];
      const char* vb = vt2[cur];

      // ---- S = Q K^T
      f32x4 s[4];
      #pragma unroll
      for (int n = 0; n < 4; ++n) s[n] = f32x4{0.f, 0.f, 0.f, 0.f};
      __builtin_amdgcn_s_setprio(1);
      #pragma unroll
      for (int kk = 0; kk < 2; ++kk) {
        #pragma unroll
        for (int n = 0; n < 4; ++n) {
          const f16x8 kf = *reinterpret_cast<const f16x8*>(
              kb + SWZB(n * 16 + l15, kk * 64 + g * 16));
          s[n] = __builtin_amdgcn_mfma_f32_16x16x32_f16(qf[kk], kf, s[n], 0, 0, 0);
        }
      }
      __builtin_amdgcn_s_setprio(0);

      // ---- causal mask on the diagonal (= last) tile
      if (t == T - 1) {
        #pragma unroll
        for (int n = 0; n < 4; ++n) {
          const int key = t * KT + n * 16 + l15;
          #pragma unroll
          for (int r = 0; r < 4; ++r) {
            if (key > qrow + 4 * g + r) s[n][r] = -INFINITY;
          }
        }
      }

      // ---- online softmax with defer-max (T13, THR=8)
      float rmax[4], rsum[4], scale[4];
      #pragma unroll
      for (int r = 0; r < 4; ++r)
        rmax[r] = fmaxf(fmaxf(s[0][r], s[1][r]), fmaxf(s[2][r], s[3][r]));
      #pragma unroll
      for (int mk = 1; mk <= 8; mk <<= 1) {
        #pragma unroll
        for (int r = 0; r < 4; ++r)
          rmax[r] = fmaxf(rmax[r], __shfl_xor(rmax[r], mk));
      }
      bool grow = false;
      #pragma unroll
      for (int r = 0; r < 4; ++r) grow |= (rmax[r] > m[r] + 8.f);
      if (__any(grow)) {
        #pragma unroll
        for (int r = 0; r < 4; ++r) {
          const float mn = fmaxf(m[r], rmax[r]);
          scale[r] = __expf(m[r] - mn);  // first tile: exp(-inf)=0
          m[r] = mn;
          lsum[r] *= scale[r];
        }
        #pragma unroll
        for (int nd = 0; nd < 4; ++nd) {
          #pragma unroll
          for (int r = 0; r < 4; ++r) o[nd][r] *= scale[r];
        }
      }
      #pragma unroll
      for (int n = 0; n < 4; ++n) {
        #pragma unroll
        for (int r = 0; r < 4; ++r) s[n][r] = __expf(s[n][r] - m[r]);
      }
      #pragma unroll
      for (int r = 0; r < 4; ++r)
        rsum[r] = (s[0][r] + s[1][r]) + (s[2][r] + s[3][r]);
      #pragma unroll
      for (int mk = 1; mk <= 8; mk <<= 1) {
        #pragma unroll
        for (int r = 0; r < 4; ++r) rsum[r] += __shfl_xor(rsum[r], mk);
      }
      #pragma unroll
      for (int r = 0; r < 4; ++r) lsum[r] += rsum[r];

      // ---- P -> per-wave LDS (f16, swizzled): C/D -> A-frag relayout
      #pragma unroll
      for (int n = 0; n < 4; ++n) {
        #pragma unroll
        for (int r = 0; r < 4; ++r) {
          *reinterpret_cast<_Float16*>(
              pw + SWZB(4 * g + r, (n * 16 + l15) * 2)) = (_Float16)s[n][r];
        }
      }
      asm volatile("s_waitcnt lgkmcnt(0)" ::: "memory");
      __builtin_amdgcn_sched_barrier(0);

      // ---- O += P V
      __builtin_amdgcn_s_setprio(1);
      #pragma unroll
      for (int kblk = 0; kblk < 2; ++kblk) {
        const f16x8 pf = *reinterpret_cast<const f16x8*>(
            pw + SWZB(l15, kblk * 64 + g * 16));
        #pragma unroll
        for (int nd = 0; nd < 4; ++nd) {
          const f16x8 vf = *reinterpret_cast<const f16x8*>(
              vb + SWZB(nd * 16 + l15, kblk * 64 + g * 16));
          o[nd] = __builtin_amdgcn_mfma_f32_16x16x32_f16(pf, vf, o[nd], 0, 0, 0);
        }
      }
      __builtin_amdgcn_s_setprio(0);
      cur ^= 1;
    }

    // ---- epilogue: O /= l, store fp32
    float inv[4];
    #pragma unroll
    for (int r = 0; r < 4; ++r) inv[r] = 1.f / lsum[r];
    #pragma unroll
    for (int nd = 0; nd < 4; ++nd) {
      #pragma unroll
      for (int r = 0; r < 4; ++r) {
        Ob[(size_t)(qrow + 4 * g + r) * Dd + nd * 16 + l15] = o[nd][r] * inv[r];
      }
    }
  }
}

// ======================= fallback (R5, no ws needed) ======================
__global__ __launch_bounds__(256)
void causal_attn_fb(const float* __restrict__ Q, const float* __restrict__ K,
                    const float* __restrict__ V, float* __restrict__ O) {
  __shared__ char ks[2][KT * 128];
  __shared__ char vt[2][Dd * 128];
  __shared__ char pl[4][16 * 128];
  const int tid = threadIdx.x, lane = tid & 63, wv = tid >> 6;
  const int l15 = lane & 15, g = lane >> 4;
  const int kg = tid & 15, dq = tid >> 4;
  const int bh = blockIdx.x / 16, pr = blockIdx.x % 16;
  const size_t base = (size_t)bh * Lq * Dd;
  const float* Qb = Q + base; const float* Kb = K + base;
  const float* Vb = V + base; float* Ob = O + base;
  char* pw = pl[wv];
  #pragma unroll 1
  for (int phase = 0; phase < 2; ++phase) {
    const int chunk = (phase == 0) ? pr : (31 - pr);
    const int row0 = chunk * 64, T = chunk + 1, qrow = row0 + wv * 16;
    f16x8 qf[2];
    #pragma unroll
    for (int kk = 0; kk < 2; ++kk) {
      const float* qp = Qb + (size_t)(qrow + l15) * Dd + kk * 32 + g * 8;
      const f32x4 a = *reinterpret_cast<const f32x4*>(qp);
      const f32x4 b = *reinterpret_cast<const f32x4*>(qp + 4);
      f16x8 q8;
      #pragma unroll
      for (int i = 0; i < 4; ++i) { q8[i] = (_Float16)a[i]; q8[i+4] = (_Float16)b[i]; }
      qf[kk] = q8;
    }
    float m[4], lsum[4]; f32x4 o[4];
    #pragma unroll
    for (int r = 0; r < 4; ++r) { m[r] = -INFINITY; lsum[r] = 0.f; }
    #pragma unroll
    for (int nd = 0; nd < 4; ++nd) o[nd] = f32x4{0.f, 0.f, 0.f, 0.f};
    {
      f32x4 kreg[4], vreg[4];
      #pragma unroll
      for (int i = 0; i < 4; ++i) {
        const int c = tid + i * 256;
        kreg[i] = *reinterpret_cast<const f32x4*>(Kb + (size_t)(c >> 4) * Dd + (c & 15) * 4);
      }
      #pragma unroll
      for (int c = 0; c < 4; ++c)
        vreg[c] = *reinterpret_cast<const f32x4*>(Vb + (size_t)(kg * 4 + c) * Dd + dq * 4);
      __syncthreads();
      #pragma unroll
      for (int i = 0; i < 4; ++i) {
        const int c = tid + i * 256;
        f16x4 h;
        #pragma unroll
        for (int j = 0; j < 4; ++j) h[j] = (_Float16)kreg[i][j];
        *reinterpret_cast<f16x4*>(ks[0] + SWZB(c >> 4, (c & 15) * 8)) = h;
      }
      #pragma unroll
      for (int j = 0; j < 4; ++j) {
        f16x4 h;
        #pragma unroll
        for (int c = 0; c < 4; ++c) h[c] = (_Float16)vreg[c][j];
        *reinterpret_cast<f16x4*>(vt[0] + SWZB(dq * 4 + j, kg * 8)) = h;
      }
    }
    int cur = 0;
    #pragma unroll 1
    for (int t = 0; t < T; ++t) {
      __syncthreads();
      const char* kb = ks[cur]; const char* vb = vt[cur];
      f32x4 kreg[4], vreg[4];
      const bool pfn = (t + 1 < T);
      if (pfn) {
        const float* Kt = Kb + (size_t)(t + 1) * KT * Dd;
        const float* Vt = Vb + (size_t)(t + 1) * KT * Dd;
        #pragma unroll
        for (int i = 0; i < 4; ++i) {
          const int c = tid + i * 256;
          kreg[i] = *reinterpret_cast<const f32x4*>(Kt + (size_t)(c >> 4) * Dd + (c & 15) * 4);
        }
        #pragma unroll
        for (int c = 0; c < 4; ++c)
          vreg[c] = *reinterpret_cast<const f32x4*>(Vt + (size_t)(kg * 4 + c) * Dd + dq * 4);
      }
      f32x4 s[4];
      #pragma unroll
      for (int n = 0; n < 4; ++n) s[n] = f32x4{0.f, 0.f, 0.f, 0.f};
      #pragma unroll
      for (int kk = 0; kk < 2; ++kk) {
        #pragma unroll
        for (int n = 0; n < 4; ++n) {
          const f16x8 kf = *reinterpret_cast<const f16x8*>(kb + SWZB(n * 16 + l15, kk * 64 + g * 16));
          s[n] = __builtin_amdgcn_mfma_f32_16x16x32_f16(qf[kk], kf, s[n], 0, 0, 0);
        }
      }
      if (t == T - 1) {
        #pragma unroll
        for (int n = 0; n < 4; ++n) {
          const int key = t * KT + n * 16 + l15;
          #pragma unroll
          for (int r = 0; r < 4; ++r)
            if (key > qrow + 4 * g + r) s[n][r] = -INFINITY;
        }
      }
      float rmax[4], rsum[4], scale[4];
      #pragma unroll
      for (int r = 0; r < 4; ++r)
        rmax[r] = fmaxf(fmaxf(s[0][r], s[1][r]), fmaxf(s[2][r], s[3][r]));
      #pragma unroll
      for (int mk = 1; mk <= 8; mk <<= 1) {
        #pragma unroll
        for (int r = 0; r < 4; ++r) rmax[r] = fmaxf(rmax[r], __shfl_xor(rmax[r], mk));
      }
      #pragma unroll
      for (int r = 0; r < 4; ++r) {
        const float mn = fmaxf(m[r], rmax[r]);
        scale[r] = __expf(m[r] - mn); m[r] = mn;
      }
      #pragma unroll
      for (int n = 0; n < 4; ++n) {
        #pragma unroll
        for (int r = 0; r < 4; ++r) s[n][r] = __expf(s[n][r] - m[r]);
      }
      #pragma unroll
      for (int r = 0; r < 4; ++r) rsum[r] = (s[0][r] + s[1][r]) + (s[2][r] + s[3][r]);
      #pragma unroll
      for (int mk = 1; mk <= 8; mk <<= 1) {
        #pragma unroll
        for (int r = 0; r < 4; ++r) rsum[r] += __shfl_xor(rsum[r], mk);
      }
      #pragma unroll
      for (int r = 0; r < 4; ++r) lsum[r] = lsum[r] * scale[r] + rsum[r];
      #pragma unroll
      for (int nd = 0; nd < 4; ++nd) {
        #pragma unroll
        for (int r = 0; r < 4; ++r) o[nd][r] *= scale[r];
      }
      #pragma unroll
      for (int n = 0; n < 4; ++n) {
        #pragma unroll
        for (int r = 0; r < 4; ++r)
          *reinterpret_cast<_Float16*>(pw + SWZB(4 * g + r, (n * 16 + l15) * 2)) = (_Float16)s[n][r];
      }
      asm volatile("s_waitcnt lgkmcnt(0)" ::: "memory");
      __builtin_amdgcn_sched_barrier(0);
      #pragma unroll
      for (int kblk = 0; kblk < 2; ++kblk) {
        const f16x8 pf = *reinterpret_cast<const f16x8*>(pw + SWZB(l15, kblk * 64 + g * 16));
        #pragma unroll
        for (int nd = 0; nd < 4; ++nd) {
          const f16x8 vf = *reinterpret_cast<const f16x8*>(vb + SWZB(nd * 16 + l15, kblk * 64 + g * 16));
          o[nd] = __builtin_amdgcn_mfma_f32_16x16x32_f16(pf, vf, o[nd], 0, 0, 0);
        }
      }
      if (pfn) {
        char* kn = ks[cur ^ 1]; char* vn = vt[cur ^ 1];
        #pragma unroll
        for (int i = 0; i < 4; ++i) {
          const int c = tid + i * 256;
          f16x4 h;
          #pragma unroll
          for (int j = 0; j < 4; ++j) h[j] = (_Float16)kreg[i][j];
          *reinterpret_cast<f16x4*>(kn + SWZB(c >> 4, (c & 15) * 8)) = h;
        }
        #pragma unroll
        for (int j = 0; j < 4; ++j) {
          f16x4 h;
          #pragma unroll
          for (int c = 0; c < 4; ++c) h[c] = (_Float16)vreg[c][j];
          *reinterpret_cast<f16x4*>(vn + SWZB(dq * 4 + j, kg * 8)) = h;
        }
      }
      cur ^= 1;
    }
    float inv[4];
    #pragma unroll
    for (int r = 0; r < 4; ++r) inv[r] = 1.f / lsum[r];
    #pragma unroll
    for (int nd = 0; nd < 4; ++nd) {
      #pragma unroll
      for (int r = 0; r < 4; ++r)
        Ob[(size_t)(qrow + 4 * g + r) * Dd + nd * 16 + l15] = o[nd][r] * inv[r];
    }
  }
}

extern "C" void kernel_launch(void* const* d_in, const int* in_sizes, int n_in,
                              void* d_out, int out_size, void* d_ws, size_t ws_size,
                              hipStream_t stream) {
  const float* q = (const float*)d_in[0];
  const float* k = (const float*)d_in[1];
  const float* v = (const float*)d_in[2];
  float* o = (float*)d_out;
  const size_t elems = (size_t)BH * Lq * Dd;
  const size_t need = elems * 2 * 2;  // Kh + VTh, f16
  if (ws_size >= need) {
    u16* Kh = (u16*)d_ws;
    u16* VTh = Kh + elems;
    attn_prep<<<dim3(2 * PREP_KB), dim3(256), 0, stream>>>(k, v, Kh, VTh);
    attn_main<<<dim3(BH * PAIRS), dim3(THREADS), 0, stream>>>(q, o, Kh, VTh);
  } else {
    causal_attn_fb<<<dim3(BH * 16), dim3(256), 0, stream>>>(q, k, v, o);
  }
  (void)in_sizes; (void)n_in; (void)out_size;
}

// Round 8
// 78.802 us; speedup vs baseline: 18.7164x; 1.0346x over previous
//
#include <hip/hip_runtime.h>
#include <math.h>

// Causal attention, B=2 H=16 L=2048 D=64, fp32 in/out, scale=1.
// R8: swapped-QK^T 32x32 structure (m214 port): S^T = mfma_32x32x16(K, Q)
// puts a full q-row in-lane -> in-register softmax (1 shfl_xor(32), no
// P-LDS round-trip); P->A-frags via cvt_pkrtz + shfl_xor(32) exchange;
// defer-max (THR=8) with LDS scale broadcast only on grow-tiles.
// 2-wave blocks (128 thr), 32 q-rows/wave, KVBLK=64, 1024 statically
// balanced blocks (chunk groups {p,31-p,p+8,23-p}: weight 66/slot).
// Prepass (K->f16, VT->f16) + global_load_lds(16) staging from R7.
// Fallback (ws too small): R5 kernel.

typedef __attribute__((ext_vector_type(8))) _Float16 f16x8;
typedef __attribute__((ext_vector_type(4))) _Float16 f16x4;
typedef __attribute__((ext_vector_type(2))) _Float16 f16x2;
typedef __attribute__((ext_vector_type(4))) float f32x4;
typedef __attribute__((ext_vector_type(16))) float f32x16;
typedef unsigned short u16;
typedef unsigned int u32;
typedef __attribute__((ext_vector_type(8))) u16 u16x8;
typedef __attribute__((ext_vector_type(4))) u32 u32x4;

constexpr int Lq = 2048;
constexpr int Dd = 64;
constexpr int KT = 64;
constexpr int BH = 32;

// swizzled byte offset inside a [row][128B] LDS tile
#define SWZB(row, bcol) ((((row) * 128) + (bcol)) ^ (((row) & 7) << 4))

#define GLOAD_LDS16(g, l)                                                     \
  __builtin_amdgcn_global_load_lds(                                           \
      (const __attribute__((address_space(1))) void*)(g),                     \
      (__attribute__((address_space(3))) void*)(l), 16, 0, 0)

static __device__ __forceinline__ u16 f2h(float x) {
  return __builtin_bit_cast(u16, (_Float16)x);
}

// ============================ prepass =====================================
// blocks [0, 1024): K fp32 -> f16 flat (16 elems/thread)
// blocks [1024, 2048): V -> VT f16 [h][d][key], 64x64 tile transpose via LDS
constexpr int PREP_KB = (BH * Lq * Dd) / (256 * 16);  // 1024

__global__ __launch_bounds__(256)
void attn_prep(const float* __restrict__ K, const float* __restrict__ V,
               u16* __restrict__ Kh, u16* __restrict__ VTh) {
  const int b = blockIdx.x;
  const int tid = threadIdx.x;
  if (b < PREP_KB) {
    const size_t base = ((size_t)b * 256 + tid) * 16;
    const f32x4* src = reinterpret_cast<const f32x4*>(K + base);
    u16x8 o0, o1;
    #pragma unroll
    for (int i = 0; i < 2; ++i) {
      const f32x4 a = src[i];
      #pragma unroll
      for (int j = 0; j < 4; ++j) o0[i * 4 + j] = f2h(a[j]);
    }
    #pragma unroll
    for (int i = 0; i < 2; ++i) {
      const f32x4 a = src[2 + i];
      #pragma unroll
      for (int j = 0; j < 4; ++j) o1[i * 4 + j] = f2h(a[j]);
    }
    *reinterpret_cast<u16x8*>(Kh + base) = o0;
    *reinterpret_cast<u16x8*>(Kh + base + 8) = o1;
  } else {
    __shared__ u16 lt[64][66];  // +2 pad -> conflict-free transpose
    const int vb = b - PREP_KB;
    const int h = vb >> 5, tt = vb & 31;
    const float* Vt = V + ((size_t)h * Lq + tt * 64) * Dd;
    const int r = tid & 63, dg = tid >> 6;
    #pragma unroll
    for (int i = 0; i < 4; ++i) {
      const f32x4 a = *reinterpret_cast<const f32x4*>(Vt + (size_t)r * Dd + dg * 16 + i * 4);
      #pragma unroll
      for (int j = 0; j < 2; ++j) {
        const unsigned two =
            (unsigned)f2h(a[2 * j]) | ((unsigned)f2h(a[2 * j + 1]) << 16);
        *reinterpret_cast<unsigned*>(&lt[r][dg * 16 + i * 4 + j * 2]) = two;
      }
    }
    __syncthreads();
    const int d = tid >> 2, kq = tid & 3;
    u16x8 w0, w1;
    #pragma unroll
    for (int j = 0; j < 8; ++j) w0[j] = lt[kq * 16 + j][d];
    #pragma unroll
    for (int j = 0; j < 8; ++j) w1[j] = lt[kq * 16 + 8 + j][d];
    u16* dst = VTh + ((size_t)h * Dd + d) * Lq + tt * 64 + kq * 16;
    *reinterpret_cast<u16x8*>(dst) = w0;
    *reinterpret_cast<u16x8*>(dst + 8) = w1;
  }
}

// ============================ main kernel =================================
// 2 waves/block, 32 q-rows/wave, one 64-row chunk per block.
__global__ __launch_bounds__(128)
void attn_main(const float* __restrict__ Q, float* __restrict__ O,
               const u16* __restrict__ Kh, const u16* __restrict__ VTh) {
  __shared__ char ks[2][8192];   // K tile [key][d] f16, swizzled, dbuf
  __shared__ char vt2[2][8192];  // VT tile [d][key] f16, swizzled, dbuf
  __shared__ float bc[2][32];    // per-wave scale/inv broadcast

  const int tid  = threadIdx.x;
  const int lane = tid & 63;
  const int wv   = tid >> 6;   // 0..1
  const int l31  = lane & 31;
  const int hi   = lane >> 5;

  // statically balanced mapping: 4 rounds j, slot i -> chunk group sums 66
  const int b = blockIdx.x;
  const int j = b >> 8;
  const int i = b & 255;
  const int h = i >> 3;
  const int p = i & 7;
  const int chunk = (j == 0) ? p : (j == 1) ? (31 - p) : (j == 2) ? (p + 8) : (23 - p);

  const float* Qb = Q + (size_t)h * Lq * Dd;
  float*       Ob = O + (size_t)h * Lq * Dd;
  const u16*   Kb = Kh + (size_t)h * Lq * Dd;
  const u16*   Vb = VTh + (size_t)h * Dd * Lq;

  const int row0 = chunk * 64;
  const int T    = chunk + 1;      // 64-key tiles; last is the diagonal
  const int qrow = row0 + wv * 32;

  // ---- Q fragments (B-operand of swapped QK^T):
  // lane holds Q[qrow+l31][kc*16 + hi*8 .. +7]
  f16x8 qf[4];
  #pragma unroll
  for (int kc = 0; kc < 4; ++kc) {
    const float* qp = Qb + (size_t)(qrow + l31) * Dd + kc * 16 + hi * 8;
    const f32x4 a = *reinterpret_cast<const f32x4*>(qp);
    const f32x4 c = *reinterpret_cast<const f32x4*>(qp + 4);
    f16x8 q8;
    #pragma unroll
    for (int e = 0; e < 4; ++e) {
      q8[e]     = (_Float16)a[e];
      q8[e + 4] = (_Float16)c[e];
    }
    qf[kc] = q8;
  }

  float m = -INFINITY, lsum = 0.f;
  f32x16 o0, o1;
  #pragma unroll
  for (int e = 0; e < 16; ++e) { o0[e] = 0.f; o1[e] = 0.f; }

  // staging geometry: LDS slot s = wv*256 + it*64 + lane (16B units);
  // row = s>>3, global col-slot = (lane&7) ^ (row&7); row&7 == lane>>3.
  const int rr = lane >> 3;
  const int c0 = (lane & 7) ^ rr;

  // ---- prologue: tile 0 -> buf 0
  #pragma unroll
  for (int it = 0; it < 4; ++it) {
    const int row = wv * 32 + it * 8 + rr;
    GLOAD_LDS16(Kb + (size_t)row * Dd + c0 * 8,
                &ks[0][wv * 4096 + it * 1024 + lane * 16]);
    GLOAD_LDS16(Vb + (size_t)row * Lq + c0 * 8,
                &vt2[0][wv * 4096 + it * 1024 + lane * 16]);
  }

  int cur = 0;
  #pragma unroll 1
  for (int t = 0; t < T; ++t) {
    __syncthreads();  // drains DMA: tile t resident in buf[cur]
    if (t + 1 < T) {  // prefetch next tile
      #pragma unroll
      for (int it = 0; it < 4; ++it) {
        const int row = wv * 32 + it * 8 + rr;
        GLOAD_LDS16(Kb + (size_t)((t + 1) * KT + row) * Dd + c0 * 8,
                    &ks[cur ^ 1][wv * 4096 + it * 1024 + lane * 16]);
        GLOAD_LDS16(Vb + (size_t)row * Lq + (t + 1) * KT + c0 * 8,
                    &vt2[cur ^ 1][wv * 4096 + it * 1024 + lane * 16]);
      }
    }
    const char* kb = ks[cur];
    const char* vb = vt2[cur];
    const bool last  = (t == T - 1);
    const bool have1 = !(last && wv == 0);  // wave0's diagonal upper subtile: all masked

    // ---- S^T = K Q^T (per 32-key subtile): col=q(l31), row=key crow(r,hi)
    f32x16 st0, st1;
    #pragma unroll
    for (int e = 0; e < 16; ++e) { st0[e] = 0.f; st1[e] = 0.f; }
    __builtin_amdgcn_s_setprio(1);
    #pragma unroll
    for (int kc = 0; kc < 4; ++kc) {
      const f16x8 kf = *reinterpret_cast<const f16x8*>(
          kb + SWZB(l31, kc * 32 + hi * 16));
      st0 = __builtin_amdgcn_mfma_f32_32x32x16_f16(kf, qf[kc], st0, 0, 0, 0);
    }
    if (have1) {
      #pragma unroll
      for (int kc = 0; kc < 4; ++kc) {
        const f16x8 kf = *reinterpret_cast<const f16x8*>(
            kb + SWZB(32 + l31, kc * 32 + hi * 16));
        st1 = __builtin_amdgcn_mfma_f32_32x32x16_f16(kf, qf[kc], st1, 0, 0, 0);
      }
    }
    __builtin_amdgcn_s_setprio(0);

    // ---- causal mask (diagonal tile): subtile ksub==wv is triangular;
    // local form: mask iff crow(r,hi) > l31.
    if (last) {
      #pragma unroll
      for (int r = 0; r < 16; ++r) {
        const int crow = (r & 3) + 8 * (r >> 2) + 4 * hi;
        if (wv == 0) { if (crow > l31) st0[r] = -INFINITY; }
        else         { if (crow > l31) st1[r] = -INFINITY; }
      }
    }

    // ---- in-register softmax with defer-max (THR=8)
    float pm = st0[0];
    #pragma unroll
    for (int r = 1; r < 16; ++r) pm = fmaxf(pm, st0[r]);
    if (have1) {
      #pragma unroll
      for (int r = 0; r < 16; ++r) pm = fmaxf(pm, st1[r]);
    }
    pm = fmaxf(pm, __shfl_xor(pm, 32));

    if (__any(pm > m + 8.f)) {
      const float mn = fmaxf(m, pm);
      const float sc = __expf(m - mn);  // first tile: exp(-inf)=0
      m = mn;
      lsum *= sc;
      if (hi == 0) bc[wv][l31] = sc;    // scale indexed by q
      const f32x4 s0 = *reinterpret_cast<const f32x4*>(&bc[wv][4 * hi]);
      const f32x4 s1 = *reinterpret_cast<const f32x4*>(&bc[wv][8 + 4 * hi]);
      const f32x4 s2 = *reinterpret_cast<const f32x4*>(&bc[wv][16 + 4 * hi]);
      const f32x4 s3 = *reinterpret_cast<const f32x4*>(&bc[wv][24 + 4 * hi]);
      #pragma unroll
      for (int r = 0; r < 16; ++r) {
        const float fac = (r < 4) ? s0[r & 3] : (r < 8) ? s1[r & 3]
                        : (r < 12) ? s2[r & 3] : s3[r & 3];
        o0[r] *= fac;
        o1[r] *= fac;
      }
    }

    float rs = 0.f;
    #pragma unroll
    for (int r = 0; r < 16; ++r) { st0[r] = __expf(st0[r] - m); rs += st0[r]; }
    if (have1) {
      #pragma unroll
      for (int r = 0; r < 16; ++r) { st1[r] = __expf(st1[r] - m); rs += st1[r]; }
    }
    rs += __shfl_xor(rs, 32);
    lsum += rs;

    // ---- P-pack (cvt_pkrtz + shfl_xor(32)) and PV, per key-subtile
    #pragma unroll
    for (int ksub = 0; ksub < 2; ++ksub) {
      if (ksub == 1 && !have1) break;
      const f32x16& st = (ksub == 0) ? st0 : st1;
      #pragma unroll
      for (int ks2 = 0; ks2 < 2; ++ks2) {
        const u32 pe0 = __builtin_bit_cast(u32,
            __builtin_amdgcn_cvt_pkrtz(st[8 * ks2 + 0], st[8 * ks2 + 1]));
        const u32 pe1 = __builtin_bit_cast(u32,
            __builtin_amdgcn_cvt_pkrtz(st[8 * ks2 + 2], st[8 * ks2 + 3]));
        const u32 po0 = __builtin_bit_cast(u32,
            __builtin_amdgcn_cvt_pkrtz(st[8 * ks2 + 4], st[8 * ks2 + 5]));
        const u32 po1 = __builtin_bit_cast(u32,
            __builtin_amdgcn_cvt_pkrtz(st[8 * ks2 + 6], st[8 * ks2 + 7]));
        const u32 re0 = __shfl_xor(pe0, 32);
        const u32 re1 = __shfl_xor(pe1, 32);
        const u32 ro0 = __shfl_xor(po0, 32);
        const u32 ro1 = __shfl_xor(po1, 32);
        u32x4 w;
        w[0] = hi ? ro0 : pe0;
        w[1] = hi ? ro1 : pe1;
        w[2] = hi ? po0 : re0;
        w[3] = hi ? po1 : re1;
        const f16x8 pa = __builtin_bit_cast(f16x8, w);
        const int cb = ksub * 64 + ks2 * 32 + hi * 16;  // key-col bytes in VT
        const f16x8 v0 = *reinterpret_cast<const f16x8*>(vb + SWZB(l31, cb));
        const f16x8 v1 = *reinterpret_cast<const f16x8*>(vb + SWZB(32 + l31, cb));
        __builtin_amdgcn_s_setprio(1);
        o0 = __builtin_amdgcn_mfma_f32_32x32x16_f16(pa, v0, o0, 0, 0, 0);
        o1 = __builtin_amdgcn_mfma_f32_32x32x16_f16(pa, v1, o1, 0, 0, 0);
        __builtin_amdgcn_s_setprio(0);
      }
    }
    cur ^= 1;
  }

  // ---- epilogue: O /= lsum; broadcast inv by q via LDS; store fp32
  const float inv = 1.f / lsum;
  if (hi == 0) bc[wv][l31] = inv;
  const f32x4 i0 = *reinterpret_cast<const f32x4*>(&bc[wv][4 * hi]);
  const f32x4 i1 = *reinterpret_cast<const f32x4*>(&bc[wv][8 + 4 * hi]);
  const f32x4 i2 = *reinterpret_cast<const f32x4*>(&bc[wv][16 + 4 * hi]);
  const f32x4 i3 = *reinterpret_cast<const f32x4*>(&bc[wv][24 + 4 * hi]);
  #pragma unroll
  for (int r = 0; r < 16; ++r) {
    const int crow = (r & 3) + 8 * (r >> 2) + 4 * hi;
    const float fac = (r < 4) ? i0[r & 3] : (r < 8) ? i1[r & 3]
                    : (r < 12) ? i2[r & 3] : i3[r & 3];
    float* op = Ob + (size_t)(qrow + crow) * Dd + l31;
    op[0]  = o0[r] * fac;
    op[32] = o1[r] * fac;
  }
}

// ======================= fallback (R5, no ws needed) ======================
__global__ __launch_bounds__(256)
void causal_attn_fb(const float* __restrict__ Q, const float* __restrict__ K,
                    const float* __restrict__ V, float* __restrict__ O) {
  __shared__ char ks[2][KT * 128];
  __shared__ char vt[2][Dd * 128];
  __shared__ char pl[4][16 * 128];
  const int tid = threadIdx.x, lane = tid & 63, wv = tid >> 6;
  const int l15 = lane & 15, g = lane >> 4;
  const int kg = tid & 15, dq = tid >> 4;
  const int bh = blockIdx.x / 16, pr = blockIdx.x % 16;
  const size_t base = (size_t)bh * Lq * Dd;
  const float* Qb = Q + base; const float* Kb = K + base;
  const float* Vb = V + base; float* Ob = O + base;
  char* pw = pl[wv];
  #pragma unroll 1
  for (int phase = 0; phase < 2; ++phase) {
    const int chunk = (phase == 0) ? pr : (31 - pr);
    const int row0 = chunk * 64, T = chunk + 1, qrow = row0 + wv * 16;
    f16x8 qf[2];
    #pragma unroll
    for (int kk = 0; kk < 2; ++kk) {
      const float* qp = Qb + (size_t)(qrow + l15) * Dd + kk * 32 + g * 8;
      const f32x4 a = *reinterpret_cast<const f32x4*>(qp);
      const f32x4 b = *reinterpret_cast<const f32x4*>(qp + 4);
      f16x8 q8;
      #pragma unroll
      for (int i = 0; i < 4; ++i) { q8[i] = (_Float16)a[i]; q8[i+4] = (_Float16)b[i]; }
      qf[kk] = q8;
    }
    float m[4], lsum[4]; f32x4 o[4];
    #pragma unroll
    for (int r = 0; r < 4; ++r) { m[r] = -INFINITY; lsum[r] = 0.f; }
    #pragma unroll
    for (int nd = 0; nd < 4; ++nd) o[nd] = f32x4{0.f, 0.f, 0.f, 0.f};
    {
      f32x4 kreg[4], vreg[4];
      #pragma unroll
      for (int i = 0; i < 4; ++i) {
        const int c = tid + i * 256;
        kreg[i] = *reinterpret_cast<const f32x4*>(Kb + (size_t)(c >> 4) * Dd + (c & 15) * 4);
      }
      #pragma unroll
      for (int c = 0; c < 4; ++c)
        vreg[c] = *reinterpret_cast<const f32x4*>(Vb + (size_t)(kg * 4 + c) * Dd + dq * 4);
      __syncthreads();
      #pragma unroll
      for (int i = 0; i < 4; ++i) {
        const int c = tid + i * 256;
        f16x4 hh;
        #pragma unroll
        for (int jj = 0; jj < 4; ++jj) hh[jj] = (_Float16)kreg[i][jj];
        *reinterpret_cast<f16x4*>(ks[0] + SWZB(c >> 4, (c & 15) * 8)) = hh;
      }
      #pragma unroll
      for (int jj = 0; jj < 4; ++jj) {
        f16x4 hh;
        #pragma unroll
        for (int c = 0; c < 4; ++c) hh[c] = (_Float16)vreg[c][jj];
        *reinterpret_cast<f16x4*>(vt[0] + SWZB(dq * 4 + jj, kg * 8)) = hh;
      }
    }
    int cur = 0;
    #pragma unroll 1
    for (int t = 0; t < T; ++t) {
      __syncthreads();
      const char* kb = ks[cur]; const char* vb = vt[cur];
      f32x4 kreg[4], vreg[4];
      const bool pfn = (t + 1 < T);
      if (pfn) {
        const float* Kt = Kb + (size_t)(t + 1) * KT * Dd;
        const float* Vt = Vb + (size_t)(t + 1) * KT * Dd;
        #pragma unroll
        for (int i = 0; i < 4; ++i) {
          const int c = tid + i * 256;
          kreg[i] = *reinterpret_cast<const f32x4*>(Kt + (size_t)(c >> 4) * Dd + (c & 15) * 4);
        }
        #pragma unroll
        for (int c = 0; c < 4; ++c)
          vreg[c] = *reinterpret_cast<const f32x4*>(Vt + (size_t)(kg * 4 + c) * Dd + dq * 4);
      }
      f32x4 s[4];
      #pragma unroll
      for (int n = 0; n < 4; ++n) s[n] = f32x4{0.f, 0.f, 0.f, 0.f};
      #pragma unroll
      for (int kk = 0; kk < 2; ++kk) {
        #pragma unroll
        for (int n = 0; n < 4; ++n) {
          const f16x8 kf = *reinterpret_cast<const f16x8*>(kb + SWZB(n * 16 + l15, kk * 64 + g * 16));
          s[n] = __builtin_amdgcn_mfma_f32_16x16x32_f16(qf[kk], kf, s[n], 0, 0, 0);
        }
      }
      if (t == T - 1) {
        #pragma unroll
        for (int n = 0; n < 4; ++n) {
          const int key = t * KT + n * 16 + l15;
          #pragma unroll
          for (int r = 0; r < 4; ++r)
            if (key > qrow + 4 * g + r) s[n][r] = -INFINITY;
        }
      }
      float rmax[4], rsum[4], scale[4];
      #pragma unroll
      for (int r = 0; r < 4; ++r)
        rmax[r] = fmaxf(fmaxf(s[0][r], s[1][r]), fmaxf(s[2][r], s[3][r]));
      #pragma unroll
      for (int mk = 1; mk <= 8; mk <<= 1) {
        #pragma unroll
        for (int r = 0; r < 4; ++r) rmax[r] = fmaxf(rmax[r], __shfl_xor(rmax[r], mk));
      }
      #pragma unroll
      for (int r = 0; r < 4; ++r) {
        const float mn = fmaxf(m[r], rmax[r]);
        scale[r] = __expf(m[r] - mn); m[r] = mn;
      }
      #pragma unroll
      for (int n = 0; n < 4; ++n) {
        #pragma unroll
        for (int r = 0; r < 4; ++r) s[n][r] = __expf(s[n][r] - m[r]);
      }
      #pragma unroll
      for (int r = 0; r < 4; ++r) rsum[r] = (s[0][r] + s[1][r]) + (s[2][r] + s[3][r]);
      #pragma unroll
      for (int mk = 1; mk <= 8; mk <<= 1) {
        #pragma unroll
        for (int r = 0; r < 4; ++r) rsum[r] += __shfl_xor(rsum[r], mk);
      }
      #pragma unroll
      for (int r = 0; r < 4; ++r) lsum[r] = lsum[r] * scale[r] + rsum[r];
      #pragma unroll
      for (int nd = 0; nd < 4; ++nd) {
        #pragma unroll
        for (int r = 0; r < 4; ++r) o[nd][r] *= scale[r];
      }
      #pragma unroll
      for (int n = 0; n < 4; ++n) {
        #pragma unroll
        for (int r = 0; r < 4; ++r)
          *reinterpret_cast<_Float16*>(pw + SWZB(4 * g + r, (n * 16 + l15) * 2)) = (_Float16)s[n][r];
      }
      asm volatile("s_waitcnt lgkmcnt(0)" ::: "memory");
      __builtin_amdgcn_sched_barrier(0);
      #pragma unroll
      for (int kblk = 0; kblk < 2; ++kblk) {
        const f16x8 pf = *reinterpret_cast<const f16x8*>(pw + SWZB(l15, kblk * 64 + g * 16));
        #pragma unroll
        for (int nd = 0; nd < 4; ++nd) {
          const f16x8 vf = *reinterpret_cast<const f16x8*>(vb + SWZB(nd * 16 + l15, kblk * 64 + g * 16));
          o[nd] = __builtin_amdgcn_mfma_f32_16x16x32_f16(pf, vf, o[nd], 0, 0, 0);
        }
      }
      if (pfn) {
        char* kn = ks[cur ^ 1]; char* vn = vt[cur ^ 1];
        #pragma unroll
        for (int i = 0; i < 4; ++i) {
          const int c = tid + i * 256;
          f16x4 hh;
          #pragma unroll
          for (int jj = 0; jj < 4; ++jj) hh[jj] = (_Float16)kreg[i][jj];
          *reinterpret_cast<f16x4*>(kn + SWZB(c >> 4, (c & 15) * 8)) = hh;
        }
        #pragma unroll
        for (int jj = 0; jj < 4; ++jj) {
          f16x4 hh;
          #pragma unroll
          for (int c = 0; c < 4; ++c) hh[c] = (_Float16)vreg[c][jj];
          *reinterpret_cast<f16x4*>(vn + SWZB(dq * 4 + jj, kg * 8)) = hh;
        }
      }
      cur ^= 1;
    }
    float inv[4];
    #pragma unroll
    for (int r = 0; r < 4; ++r) inv[r] = 1.f / lsum[r];
    #pragma unroll
    for (int nd = 0; nd < 4; ++nd) {
      #pragma unroll
      for (int r = 0; r < 4; ++r)
        Ob[(size_t)(qrow + 4 * g + r) * Dd + nd * 16 + l15] = o[nd][r] * inv[r];
    }
  }
}

extern "C" void kernel_launch(void* const* d_in, const int* in_sizes, int n_in,
                              void* d_out, int out_size, void* d_ws, size_t ws_size,
                              hipStream_t stream) {
  const float* q = (const float*)d_in[0];
  const float* k = (const float*)d_in[1];
  const float* v = (const float*)d_in[2];
  float* o = (float*)d_out;
  const size_t elems = (size_t)BH * Lq * Dd;
  const size_t need = elems * 2 * 2;  // Kh + VTh, f16
  if (ws_size >= need) {
    u16* Kh = (u16*)d_ws;
    u16* VTh = Kh + elems;
    attn_prep<<<dim3(2 * PREP_KB), dim3(256), 0, stream>>>(k, v, Kh, VTh);
    attn_main<<<dim3(BH * 32), dim3(128), 0, stream>>>(q, o, Kh, VTh);
  } else {
    causal_attn_fb<<<dim3(BH * 16), dim3(256), 0, stream>>>(q, k, v, o);
  }
  (void)in_sizes; (void)n_in; (void)out_size;
}